// Round 3
// baseline (549.826 us; speedup 1.0000x reference)
//
#include <hip/hip_runtime.h>

// GRAM model: ontology attention (MFMA) -> embedding projection (MFMA) -> GRU -> softmax
// Sizes: T=50 B=128 V=8000 NEMB=8728 E=128 H=128 ATT=100 C=283 L=5, M=T*B=6400
// dtypes: float tensors fp32 (inputs AND output); leaves/ancestors int32.

typedef unsigned short u16;
typedef unsigned int   u32;
typedef short bf16x8 __attribute__((ext_vector_type(8)));
typedef float f32x4  __attribute__((ext_vector_type(4)));

typedef __attribute__((address_space(1))) u32 gas_u32;
typedef __attribute__((address_space(3))) u32 las_u32;

union U4 { u32 u[4]; bf16x8 v; uint4 q; };

__device__ __forceinline__ float uaf(u32 u){ union{u32 u; float f;} c; c.u=u; return c.f; }
__device__ __forceinline__ u32 fau(float f){ union{u32 u; float f;} c; c.f=f; return c.u; }
__device__ __forceinline__ u16 f2bf(float f){ u32 u=fau(f); return (u16)((u + 0x7fffu + ((u>>16)&1u))>>16); }
__device__ __forceinline__ float sigm(float x){ return 1.f/(1.f+__expf(-x)); }

__device__ __forceinline__ void gll16(const void* g, void* l){
    __builtin_amdgcn_global_load_lds((const gas_u32*)g, (las_u32*)l, 16, 0, 0);
}

// split 8 consecutive floats into bf16-hi and bf16-lo packed fragments (RNE)
__device__ __forceinline__ void split8(const float* f, bf16x8* hi, bf16x8* lo){
    U4 H, L;
    #pragma unroll
    for (int j=0;j<4;++j){
        float f0=f[2*j], f1=f[2*j+1];
        u32 u0=fau(f0), u1=fau(f1);
        u32 t0=u0+0x7fffu+((u0>>16)&1u);
        u32 t1=u1+0x7fffu+((u1>>16)&1u);
        u32 h1=t1&0xffff0000u;
        H.u[j]=(t0>>16)|h1;
        float l0=f0-uaf(t0&0xffff0000u);
        float l1=f1-uaf(h1);
        u32 v0=fau(l0), v1=fau(l1);
        u32 s0=v0+0x7fffu+((v0>>16)&1u);
        u32 s1=v1+0x7fffu+((v1>>16)&1u);
        L.u[j]=(s0>>16)|(s1&0xffff0000u);
    }
    *hi=H.v; *lo=L.v;
}

__device__ __forceinline__ void split1(float f, u16& h, u16& l){
    u32 u=fau(f); u32 t=u+0x7fffu+((u>>16)&1u); h=(u16)(t>>16);
    float lf=f-uaf(t&0xffff0000u); l=f2bf(lf);
}

#define MFMA(a,b,c) __builtin_amdgcn_mfma_f32_16x16x32_bf16(a,b,c,0,0,0)

// ---------------------------------------------------------------------------
// prep: W_att [256][100] fp32 -> WT_h/WT_l [112][256] bf16 (rows >=100 zero)
__global__ __launch_bounds__(256,1) void prep_watt_kernel(
    const float* __restrict__ W_att, u16* __restrict__ WT_h, u16* __restrict__ WT_l)
{
    int n=blockIdx.x, k=threadIdx.x;          // n<112, k<256
    float f = (n<100)? W_att[k*100+n] : 0.f;
    u16 h,l; split1(f,h,l);
    WT_h[n*256+k]=h; WT_l[n*256+k]=l;
}

// prep: w_hh [384][128] fp32 -> bf16 pairs u32[384*64]
__global__ __launch_bounds__(256,1) void prep_whh_kernel(
    const float* __restrict__ whh, u32* __restrict__ out)
{
    int i=blockIdx.x*256+threadIdx.x;         // < 24576
    int j=i>>6, p=i&63;
    u32 a=(u32)f2bf(whh[j*128+2*p]);
    u32 b=(u32)f2bf(whh[j*128+2*p+1]);
    out[i]=a|(b<<16);
}

// prep: w_ihT[e][j] = w_ih[j][e] fp32
__global__ __launch_bounds__(256,1) void transpose_wih_kernel(
    const float* __restrict__ w_ih, float* __restrict__ w_ihT)
{
    int i=blockIdx.x*256+threadIdx.x;         // < 49152
    int e=i/384, j=i-e*384;
    w_ihT[i]=w_ih[j*128+e];
}

// ---------------------------------------------------------------------------
// Phase 1: attention MLP via MFMA + softmax over L + emb reduce (fp32).
// One block = 25 leaf codes = 125 (v,l) rows (pad to 128). N=112 (100 used), K=256.
// ---------------------------------------------------------------------------
__global__ __launch_bounds__(256,1) void attn_mlp_kernel(
    const float* __restrict__ W_emb, const float* __restrict__ b_att,
    const float* __restrict__ v_att, const int* __restrict__ leaves,
    const int* __restrict__ anc, const u16* __restrict__ WT_h,
    const u16* __restrict__ WT_l, float* __restrict__ emb_f)
{
    __shared__ __align__(16) char smem[61440];
    short* Ah=(short*)smem;                 // [128][64] bf16  16384 B
    short* Al=(short*)(smem+16384);         // 16384 B
    short* Bh=(short*)(smem+32768);         // [112][64] 14336 B
    short* Bl=(short*)(smem+47104);         // 14336 B
    float* mlp_s=(float*)smem;              // [128][112] fp32 (after MFMA, 57344 B)
    __shared__ float s_pre[128];
    __shared__ float s_vatt[112];
    __shared__ float s_attw[128];
    __shared__ int   s_leaf[128], s_anc[128];

    const int tid=threadIdx.x;
    const int wave=tid>>6, lane=tid&63;
    const int vb5=blockIdx.x*125;           // first (v,l) flat row

    if (tid<125){ s_leaf[tid]=leaves[vb5+tid]; s_anc[tid]=anc[vb5+tid]; }
    else if (tid<128){ s_leaf[tid]=leaves[vb5]; s_anc[tid]=anc[vb5]; }
    if (tid<100) s_vatt[tid]=v_att[tid];

    f32x4 acc[2][7];
    const f32x4 zf={0.f,0.f,0.f,0.f};
    #pragma unroll
    for (int mi=0;mi<2;++mi)
        #pragma unroll
        for (int ni=0;ni<7;++ni) acc[mi][ni]=zf;

    const int fr=lane&15, fq=lane>>4;

    for (int kc=0;kc<4;++kc){               // K chunks of 64: 0,1=leaf half, 2,3=anc half
        __syncthreads();
        {   // A: gather + hi/lo split; thread -> (row r=tid>>1, seg=tid&1: 32 floats)
            int r=tid>>1, seg=tid&1;
            int src=(kc<2)? s_leaf[r] : s_anc[r];
            const float* srcp = W_emb + (size_t)src*128 + (kc&1)*64 + seg*32;
            float buf[32];
            #pragma unroll
            for (int i=0;i<8;++i) *(f32x4*)(buf+4*i) = *(const f32x4*)(srcp+4*i);
            #pragma unroll
            for (int j=0;j<4;++j){
                bf16x8 hv, lv; split8(buf+8*j, &hv, &lv);
                U4 H,L; H.v=hv; L.v=lv;
                *(uint4*)&Ah[r*64+seg*32+j*8] = H.q;
                *(uint4*)&Al[r*64+seg*32+j*8] = L.q;
            }
        }
        // B: async global->LDS (rows are n, cols k-chunk)
        for (int c=wave;c<14;c+=4){
            size_t go=(size_t)(c*8+(lane>>3))*512 + (size_t)kc*128 + (size_t)(lane&7)*16;
            gll16((const char*)WT_h+go, Bh+c*512);
            gll16((const char*)WT_l+go, Bl+c*512);
        }
        __syncthreads();

        #pragma unroll
        for (int ks=0;ks<2;++ks){
            bf16x8 ah[2],al[2],bh[7],bl[7];
            #pragma unroll
            for (int mi=0;mi<2;++mi){
                int row=wave*32+mi*16+fr;
                ah[mi]=*(const bf16x8*)&Ah[row*64+ks*32+fq*8];
                al[mi]=*(const bf16x8*)&Al[row*64+ks*32+fq*8];
            }
            #pragma unroll
            for (int ni=0;ni<7;++ni){
                int rowb=ni*16+fr;
                bh[ni]=*(const bf16x8*)&Bh[rowb*64+ks*32+fq*8];
                bl[ni]=*(const bf16x8*)&Bl[rowb*64+ks*32+fq*8];
            }
            #pragma unroll
            for (int mi=0;mi<2;++mi)
                #pragma unroll
                for (int ni=0;ni<7;++ni){
                    acc[mi][ni]=MFMA(ah[mi],bh[ni],acc[mi][ni]);
                    acc[mi][ni]=MFMA(ah[mi],bl[ni],acc[mi][ni]);
                    acc[mi][ni]=MFMA(al[mi],bh[ni],acc[mi][ni]);
                }
        }
    }
    __syncthreads();
    // mlp = tanh(acc + b_att) -> LDS (C/D layout: col=lane&15, row=quad*4+reg)
    #pragma unroll
    for (int ni=0;ni<7;++ni){
        int col=ni*16+fr;
        float bb=(col<100)? b_att[col] : 0.f;
        #pragma unroll
        for (int mi=0;mi<2;++mi){
            int rb=wave*32+mi*16+fq*4;
            #pragma unroll
            for (int r=0;r<4;++r)
                mlp_s[(rb+r)*112+col]=tanhf(acc[mi][ni][r]+bb);
        }
    }
    __syncthreads();
    if (tid<128){
        float s=0.f;
        for (int n=0;n<100;++n) s+=mlp_s[tid*112+n]*s_vatt[n];
        s_pre[tid]=s;
    }
    __syncthreads();
    if (tid<25){    // softmax over L=5
        float p[5], mx=-1e30f;
        #pragma unroll
        for (int l=0;l<5;++l){ p[l]=s_pre[tid*5+l]; mx=fmaxf(mx,p[l]); }
        float s=0.f;
        #pragma unroll
        for (int l=0;l<5;++l){ p[l]=__expf(p[l]-mx); s+=p[l]; }
        float inv=1.f/s;
        #pragma unroll
        for (int l=0;l<5;++l) s_attw[tid*5+l]=p[l]*inv;
    }
    __syncthreads();
    for (int o=tid;o<3200;o+=256){   // emb[v][e] = sum_l att * an (fp32)
        int v=o>>7, e=o&127;
        float s=0.f;
        #pragma unroll
        for (int l=0;l<5;++l)
            s += s_attw[v*5+l]*W_emb[(size_t)s_anc[v*5+l]*128+e];
        emb_f[(size_t)(blockIdx.x*25+v)*128+e]=s;
    }
}

// ---------------------------------------------------------------------------
// Phase 1b: emb fp32 [8000][128] -> transposed bf16 hi/lo [128][8000]
__global__ __launch_bounds__(256,1) void emb_split_kernel(
    const float* __restrict__ emb_f, u16* __restrict__ hiT, u16* __restrict__ loT)
{
    __shared__ float tile[64*128];
    const int tid=threadIdx.x;
    const int vb=blockIdx.x*64;
    for (int i=tid;i<2048;i+=256){
        int row=i>>5, q=i&31;
        *(f32x4*)&tile[row*128+q*4] = *(const f32x4*)&emb_f[(size_t)(vb+row)*128+q*4];
    }
    __syncthreads();
    u32* hw=(u32*)hiT; u32* lw=(u32*)loT;
    for (int o=tid;o<4096;o+=256){
        int e=o>>5, p=o&31;
        float f0=tile[(2*p)*128+e], f1=tile[(2*p+1)*128+e];
        u16 h0,l0,h1,l1; split1(f0,h0,l0); split1(f1,h1,l1);
        size_t base=(size_t)e*4000 + (size_t)(vb>>1) + p;
        hw[base]=(u32)h0|((u32)h1<<16);
        lw[base]=(u32)l0|((u32)l1<<16);
    }
}

// ---------------------------------------------------------------------------
// Phase 2: partials[ks][m][e] = x[m, k-slice] @ emb[k-slice, e]
// x staged fp32 via global_load_lds; converted to bf16 hi/lo in regs; 3-combo MFMA.
// ---------------------------------------------------------------------------
__global__ __launch_bounds__(256,1) void gemm_xemb_kernel(
    const float* __restrict__ x, const u16* __restrict__ bhT, const u16* __restrict__ blT,
    float* __restrict__ partials)
{
    __shared__ __align__(16) float Asf[128*64];   // 32 KB fp32
    __shared__ __align__(16) short Bh[128*64];    // 16 KB
    __shared__ __align__(16) short Bl[128*64];    // 16 KB

    const int tid=threadIdx.x, wave=tid>>6, lane=tid&63;
    const int mt=blockIdx.x%50, ks=blockIdx.x/50;
    const int mbase=mt*128;
    const int k0=ks*1600;

    f32x4 acc[4][4];
    const f32x4 zf={0.f,0.f,0.f,0.f};
    #pragma unroll
    for (int i=0;i<4;++i)
        #pragma unroll
        for (int j=0;j<4;++j) acc[i][j]=zf;

    const char* xb=(const char*)x;
    const char* bhb=(const char*)bhT;
    const char* blb=(const char*)blT;
    const int mrow=(wave>>1)*64, ncol=(wave&1)*64;
    const int fr=lane&15, fq=lane>>4;

    for (int kk=k0; kk<k0+1600; kk+=64){
        __syncthreads();
        #pragma unroll
        for (int cc=0;cc<8;++cc){                 // A fp32: 32 chunks of 4 rows
            int c=wave*8+cc;
            int row=c*4+(lane>>4);
            gll16(xb + (size_t)(mbase+row)*32000 + (size_t)kk*4 + (size_t)(lane&15)*16,
                  &Asf[c*256]);
        }
        #pragma unroll
        for (int cc=0;cc<4;++cc){                 // B bf16: 16 chunks of 8 rows
            int c=wave*4+cc;
            int row=c*8+(lane>>3);
            size_t go=(size_t)row*16000 + (size_t)kk*2 + (size_t)(lane&7)*16;
            gll16(bhb+go, &Bh[c*512]);
            gll16(blb+go, &Bl[c*512]);
        }
        __syncthreads();

        #pragma unroll
        for (int kh=0;kh<2;++kh){
            bf16x8 ah[4],al[4],bh[4],bl[4];
            #pragma unroll
            for (int i=0;i<4;++i)
                split8(&Asf[(mrow+i*16+fr)*64 + kh*32 + fq*8], &ah[i], &al[i]);
            #pragma unroll
            for (int j=0;j<4;++j){
                bh[j]=*(const bf16x8*)&Bh[(ncol+j*16+fr)*64+kh*32+fq*8];
                bl[j]=*(const bf16x8*)&Bl[(ncol+j*16+fr)*64+kh*32+fq*8];
            }
            #pragma unroll
            for (int i=0;i<4;++i)
                #pragma unroll
                for (int j=0;j<4;++j){
                    acc[i][j]=MFMA(ah[i],bh[j],acc[i][j]);
                    acc[i][j]=MFMA(ah[i],bl[j],acc[i][j]);
                    acc[i][j]=MFMA(al[i],bh[j],acc[i][j]);
                }
        }
    }

    float* pout=partials + ((size_t)ks*6400+mbase)*128;
    #pragma unroll
    for (int i=0;i<4;++i)
        #pragma unroll
        for (int j=0;j<4;++j)
            #pragma unroll
            for (int r=0;r<4;++r)
                pout[(size_t)(mrow+i*16+fq*4+r)*128 + ncol+j*16+fr]=acc[i][j][r];
}

// Phase 2b: x_emb = tanh(sum over 5 K-split partials)
__global__ __launch_bounds__(256,1) void sum_tanh_kernel(
    const float* __restrict__ partials, float* __restrict__ x_emb)
{
    int i=blockIdx.x*256+threadIdx.x;             // < 819200
    float s=0.f;
    #pragma unroll
    for (int k=0;k<5;++k) s+=partials[(size_t)k*819200+i];
    x_emb[i]=tanhf(s);
}

// ---------------------------------------------------------------------------
// Phase 3a: GX[m][j] = x_emb[m,:] @ w_ih[j,:] + b_ih[j]
__global__ __launch_bounds__(128,1) void gx_gemm_kernel(
    const float* __restrict__ x_emb, const float* __restrict__ w_ihT,
    const float* __restrict__ b_ih, float* __restrict__ GX)
{
    __shared__ float sx[2048];
    const int tid=threadIdx.x;
    const int rb=blockIdx.x*16;
    for (int i=tid;i<2048;i+=128) sx[i]=x_emb[(size_t)rb*128+i];
    __syncthreads();

    float acc0[16],acc1[16],acc2[16];
    #pragma unroll
    for (int r=0;r<16;++r){ acc0[r]=0.f; acc1[r]=0.f; acc2[r]=0.f; }
    for (int e=0;e<128;++e){
        float w0=w_ihT[e*384+tid];
        float w1=w_ihT[e*384+tid+128];
        float w2=w_ihT[e*384+tid+256];
        #pragma unroll
        for (int r=0;r<16;++r){
            float xv=sx[r*128+e];
            acc0[r]=fmaf(xv,w0,acc0[r]);
            acc1[r]=fmaf(xv,w1,acc1[r]);
            acc2[r]=fmaf(xv,w2,acc2[r]);
        }
    }
    float b0=b_ih[tid], b1=b_ih[tid+128], b2=b_ih[tid+256];
    #pragma unroll
    for (int r=0;r<16;++r){
        float* gp=GX+(size_t)(rb+r)*384;
        gp[tid]=acc0[r]+b0;
        gp[tid+128]=acc1[r]+b1;
        gp[tid+256]=acc2[r]+b2;
    }
}

// Phase 3b: GRU scan, one block per batch element; w_hh cached as bf16 pairs.
__global__ __launch_bounds__(384,1) void gru_scan_kernel(
    const u32* __restrict__ whh_p, const float* __restrict__ b_hh,
    const float* __restrict__ GX, float* __restrict__ hidden)
{
    __shared__ __align__(16) float sh[128];
    __shared__ float sgh[384];
    __shared__ float sgx[384];
    const int tid=threadIdx.x, b=blockIdx.x;

    u32 wreg[64];
    #pragma unroll
    for (int p=0;p<64;++p) wreg[p]=whh_p[tid*64+p];
    if (tid<128) sh[tid]=0.f;
    const float bb=b_hh[tid];
    __syncthreads();

    const f32x4* sh4=(const f32x4*)sh;
    for (int t=0;t<50;++t){
        float acc=0.f;
        #pragma unroll
        for (int q=0;q<32;++q){
            f32x4 h4=sh4[q];
            u32 a=wreg[2*q], c=wreg[2*q+1];
            acc=fmaf(uaf(a<<16),        h4.x,acc);
            acc=fmaf(uaf(a&0xffff0000u),h4.y,acc);
            acc=fmaf(uaf(c<<16),        h4.z,acc);
            acc=fmaf(uaf(c&0xffff0000u),h4.w,acc);
        }
        sgh[tid]=acc+bb;
        sgx[tid]=GX[((size_t)t*128+b)*384+tid];
        __syncthreads();
        if (tid<128){
            float r=sigm(sgx[tid]+sgh[tid]);
            float z=sigm(sgx[128+tid]+sgh[128+tid]);
            float n=tanhf(sgx[256+tid]+r*sgh[256+tid]);
            float hn=(1.f-z)*n+z*sh[tid];
            hidden[((size_t)t*128+b)*128+tid]=hn;
            sh[tid]=hn;
        }
        __syncthreads();
    }
}

// ---------------------------------------------------------------------------
// Phase 4a: logits[m][c] = hidden[m,:] @ W_out[:,c] + b_out[c]
__global__ __launch_bounds__(128,1) void logits_kernel(
    const float* __restrict__ hidden, const float* __restrict__ W_out,
    const float* __restrict__ b_out, float* __restrict__ logits)
{
    __shared__ float shd[2048];
    const int tid=threadIdx.x;
    const int rb=blockIdx.x*16;
    for (int i=tid;i<2048;i+=128) shd[i]=hidden[(size_t)rb*128+i];
    __syncthreads();

    const int c0=tid, c1=tid+128, c2=tid+256;
    const bool v2=(c2<283);
    float acc0[16],acc1[16],acc2[16];
    #pragma unroll
    for (int r=0;r<16;++r){ acc0[r]=0.f; acc1[r]=0.f; acc2[r]=0.f; }
    for (int h=0;h<128;++h){
        const float* wr=W_out+h*283;
        float w0=wr[c0];
        float w1=wr[c1];
        float w2=v2? wr[c2] : 0.f;
        #pragma unroll
        for (int r=0;r<16;++r){
            float hv=shd[r*128+h];
            acc0[r]=fmaf(hv,w0,acc0[r]);
            acc1[r]=fmaf(hv,w1,acc1[r]);
            acc2[r]=fmaf(hv,w2,acc2[r]);
        }
    }
    float b0=b_out[c0], b1=b_out[c1], b2v=v2? b_out[c2] : 0.f;
    #pragma unroll
    for (int r=0;r<16;++r){
        float* lp=logits+(size_t)(rb+r)*283;
        lp[c0]=acc0[r]+b0;
        lp[c1]=acc1[r]+b1;
        if (v2) lp[c2]=acc2[r]+b2v;
    }
}

// Phase 4b: row softmax over C=283, * mask, write fp32. One wave per row.
__global__ __launch_bounds__(256,1) void softmax_mask_kernel(
    const float* __restrict__ logits, const float* __restrict__ mask,
    float* __restrict__ out)
{
    const int wave=threadIdx.x>>6, lane=threadIdx.x&63;
    const int m=blockIdx.x*4+wave;                 // < 6400
    const float* lp=logits+(size_t)m*283;
    float v[5];
    float mx=-1e30f;
    #pragma unroll
    for (int i=0;i<5;++i){
        int c=lane+i*64;
        v[i]=(c<283)? lp[c] : -1e30f;
        mx=fmaxf(mx,v[i]);
    }
    #pragma unroll
    for (int off=32;off>0;off>>=1) mx=fmaxf(mx,__shfl_xor(mx,off,64));
    float s=0.f;
    #pragma unroll
    for (int i=0;i<5;++i){
        int c=lane+i*64;
        v[i]=(c<283)? __expf(v[i]-mx) : 0.f;
        s+=v[i];
    }
    #pragma unroll
    for (int off=32;off>0;off>>=1) s+=__shfl_xor(s,off,64);
    const float sc=mask[m]/s;
    float* op=out+(size_t)m*283;
    #pragma unroll
    for (int i=0;i<5;++i){
        int c=lane+i*64;
        if (c<283) op[c]=v[i]*sc;
    }
}

// ---------------------------------------------------------------------------
extern "C" void kernel_launch(void* const* d_in, const int* in_sizes, int n_in,
                              void* d_out, int out_size, void* d_ws, size_t ws_size,
                              hipStream_t stream) {
    const float* x      = (const float*)d_in[0];    // [50,128,8000]
    const float* mask   = (const float*)d_in[1];    // [50,128]
    const float* W_emb  = (const float*)d_in[2];    // [8728,128]
    const float* W_att  = (const float*)d_in[3];    // [256,100]
    const float* b_att  = (const float*)d_in[4];    // [100]
    const float* v_att  = (const float*)d_in[5];    // [100]
    const float* w_ih   = (const float*)d_in[6];    // [384,128]
    const float* w_hh   = (const float*)d_in[7];    // [384,128]
    const float* b_ih   = (const float*)d_in[8];    // [384]
    const float* b_hh   = (const float*)d_in[9];    // [384]
    const float* W_out  = (const float*)d_in[10];   // [128,283]
    const float* b_out  = (const float*)d_in[11];   // [283]
    const int* leaves   = (const int*)d_in[12];     // [8000,5]
    const int* anc      = (const int*)d_in[13];     // [8000,5]
    float* out = (float*)d_out;                     // [50,128,283] fp32

    char* w = (char*)d_ws;
    u16*   WT_h    = (u16*)(w + 0);                 //    57,344
    u16*   WT_l    = (u16*)(w + 57344);             //    57,344
    u32*   whh_p   = (u32*)(w + 114688);            //    98,304
    float* w_ihT   = (float*)(w + 212992);          //   196,608
    u16*   emb_hiT = (u16*)(w + 409600);            // 2,048,000
    u16*   emb_loT = (u16*)(w + 2457600);           // 2,048,000
    float* x_emb   = (float*)(w + 4505600);         // 3,276,800
    float* hidden  = (float*)(w + 7782400);         // 3,276,800
    // overlay @ 11,059,200 (16,384,000 B): emb_f32 -> partials -> GX -> logits
    float* emb_f   = (float*)(w + 11059200);        // 4,096,000 (dead after emb_split)
    float* partials= (float*)(w + 11059200);        // [5][6400][128] f32
    float* GX      = (float*)(w + 11059200);        // [6400][384] f32
    float* logits  = (float*)(w + 11059200);        // [6400][283] f32

    prep_watt_kernel<<<112, 256, 0, stream>>>(W_att, WT_h, WT_l);
    prep_whh_kernel<<<96, 256, 0, stream>>>(w_hh, whh_p);
    transpose_wih_kernel<<<192, 256, 0, stream>>>(w_ih, w_ihT);
    attn_mlp_kernel<<<320, 256, 0, stream>>>(W_emb, b_att, v_att, leaves, anc,
                                             WT_h, WT_l, emb_f);
    emb_split_kernel<<<125, 256, 0, stream>>>(emb_f, emb_hiT, emb_loT);
    gemm_xemb_kernel<<<250, 256, 0, stream>>>(x, emb_hiT, emb_loT, partials);
    sum_tanh_kernel<<<3200, 256, 0, stream>>>(partials, x_emb);
    gx_gemm_kernel<<<400, 128, 0, stream>>>(x_emb, w_ihT, b_ih, GX);
    gru_scan_kernel<<<128, 384, 0, stream>>>(whh_p, b_hh, GX, hidden);
    logits_kernel<<<400, 128, 0, stream>>>(hidden, W_out, b_out, logits);
    softmax_mask_kernel<<<1600, 256, 0, stream>>>(logits, mask, out);
}

// Round 4
// 529.251 us; speedup vs baseline: 1.0389x; 1.0389x over previous
//
#include <hip/hip_runtime.h>

// GRAM model: ontology attention (MFMA) -> embedding projection (MFMA) -> GRU -> softmax
// Sizes: T=50 B=128 V=8000 NEMB=8728 E=128 H=128 ATT=100 C=283 L=5, M=T*B=6400
// dtypes: float tensors fp32 (inputs AND output); leaves/ancestors int32.

typedef unsigned short u16;
typedef unsigned int   u32;
typedef short bf16x8 __attribute__((ext_vector_type(8)));
typedef float f32x4  __attribute__((ext_vector_type(4)));

typedef __attribute__((address_space(1))) u32 gas_u32;
typedef __attribute__((address_space(3))) u32 las_u32;

union U4 { u32 u[4]; bf16x8 v; uint4 q; };

__device__ __forceinline__ float uaf(u32 u){ union{u32 u; float f;} c; c.u=u; return c.f; }
__device__ __forceinline__ u32 fau(float f){ union{u32 u; float f;} c; c.f=f; return c.u; }
__device__ __forceinline__ u16 f2bf(float f){ u32 u=fau(f); return (u16)((u + 0x7fffu + ((u>>16)&1u))>>16); }
__device__ __forceinline__ float sigm(float x){ return 1.f/(1.f+__expf(-x)); }

__device__ __forceinline__ void gll16(const void* g, void* l){
    __builtin_amdgcn_global_load_lds((const gas_u32*)g, (las_u32*)l, 16, 0, 0);
}

// split 8 consecutive floats into bf16-hi and bf16-lo packed fragments (RNE)
__device__ __forceinline__ void split8(const float* f, bf16x8* hi, bf16x8* lo){
    U4 H, L;
    #pragma unroll
    for (int j=0;j<4;++j){
        float f0=f[2*j], f1=f[2*j+1];
        u32 u0=fau(f0), u1=fau(f1);
        u32 t0=u0+0x7fffu+((u0>>16)&1u);
        u32 t1=u1+0x7fffu+((u1>>16)&1u);
        u32 h1=t1&0xffff0000u;
        H.u[j]=(t0>>16)|h1;
        float l0=f0-uaf(t0&0xffff0000u);
        float l1=f1-uaf(h1);
        u32 v0=fau(l0), v1=fau(l1);
        u32 s0=v0+0x7fffu+((v0>>16)&1u);
        u32 s1=v1+0x7fffu+((v1>>16)&1u);
        L.u[j]=(s0>>16)|(s1&0xffff0000u);
    }
    *hi=H.v; *lo=L.v;
}

__device__ __forceinline__ void split1(float f, u16& h, u16& l){
    u32 u=fau(f); u32 t=u+0x7fffu+((u>>16)&1u); h=(u16)(t>>16);
    float lf=f-uaf(t&0xffff0000u); l=f2bf(lf);
}

#define MFMA(a,b,c) __builtin_amdgcn_mfma_f32_16x16x32_bf16(a,b,c,0,0,0)

// ---------------------------------------------------------------------------
// prep: W_att [256][100] fp32 -> WT_h/WT_l [112][256] bf16 (rows >=100 zero)
__global__ __launch_bounds__(256,1) void prep_watt_kernel(
    const float* __restrict__ W_att, u16* __restrict__ WT_h, u16* __restrict__ WT_l)
{
    int n=blockIdx.x, k=threadIdx.x;          // n<112, k<256
    float f = (n<100)? W_att[k*100+n] : 0.f;
    u16 h,l; split1(f,h,l);
    WT_h[n*256+k]=h; WT_l[n*256+k]=l;
}

// prep: w_hh [384][128] fp32 -> bf16 pairs u32[384*64]
__global__ __launch_bounds__(256,1) void prep_whh_kernel(
    const float* __restrict__ whh, u32* __restrict__ out)
{
    int i=blockIdx.x*256+threadIdx.x;         // < 24576
    int j=i>>6, p=i&63;
    u32 a=(u32)f2bf(whh[j*128+2*p]);
    u32 b=(u32)f2bf(whh[j*128+2*p+1]);
    out[i]=a|(b<<16);
}

// prep: w_ihT[e][j] = w_ih[j][e] fp32
__global__ __launch_bounds__(256,1) void transpose_wih_kernel(
    const float* __restrict__ w_ih, float* __restrict__ w_ihT)
{
    int i=blockIdx.x*256+threadIdx.x;         // < 49152
    int e=i/384, j=i-e*384;
    w_ihT[i]=w_ih[j*128+e];
}

// ---------------------------------------------------------------------------
// Phase 1: attention MLP via MFMA + softmax over L + emb reduce (fp32).
// One block = 25 leaf codes = 125 (v,l) rows (pad to 128). N=112 (100 used), K=256.
// ---------------------------------------------------------------------------
__global__ __launch_bounds__(256,1) void attn_mlp_kernel(
    const float* __restrict__ W_emb, const float* __restrict__ b_att,
    const float* __restrict__ v_att, const int* __restrict__ leaves,
    const int* __restrict__ anc, const u16* __restrict__ WT_h,
    const u16* __restrict__ WT_l, float* __restrict__ emb_f)
{
    __shared__ __align__(16) char smem[61440];
    short* Ah=(short*)smem;                 // [128][64] bf16  16384 B
    short* Al=(short*)(smem+16384);         // 16384 B
    short* Bh=(short*)(smem+32768);         // [112][64] 14336 B
    short* Bl=(short*)(smem+47104);         // 14336 B
    float* mlp_s=(float*)smem;              // [128][112] fp32 (after MFMA, 57344 B)
    __shared__ float s_pre[128];
    __shared__ float s_vatt[112];
    __shared__ float s_attw[128];
    __shared__ int   s_leaf[128], s_anc[128];

    const int tid=threadIdx.x;
    const int wave=tid>>6, lane=tid&63;
    const int vb5=blockIdx.x*125;           // first (v,l) flat row

    if (tid<125){ s_leaf[tid]=leaves[vb5+tid]; s_anc[tid]=anc[vb5+tid]; }
    else if (tid<128){ s_leaf[tid]=leaves[vb5]; s_anc[tid]=anc[vb5]; }
    if (tid<100) s_vatt[tid]=v_att[tid];

    f32x4 acc[2][7];
    const f32x4 zf={0.f,0.f,0.f,0.f};
    #pragma unroll
    for (int mi=0;mi<2;++mi)
        #pragma unroll
        for (int ni=0;ni<7;++ni) acc[mi][ni]=zf;

    const int fr=lane&15, fq=lane>>4;

    for (int kc=0;kc<4;++kc){               // K chunks of 64: 0,1=leaf half, 2,3=anc half
        __syncthreads();
        {   // A: gather + hi/lo split; thread -> (row r=tid>>1, seg=tid&1: 32 floats)
            int r=tid>>1, seg=tid&1;
            int src=(kc<2)? s_leaf[r] : s_anc[r];
            const float* srcp = W_emb + (size_t)src*128 + (kc&1)*64 + seg*32;
            float buf[32];
            #pragma unroll
            for (int i=0;i<8;++i) *(f32x4*)(buf+4*i) = *(const f32x4*)(srcp+4*i);
            #pragma unroll
            for (int j=0;j<4;++j){
                bf16x8 hv, lv; split8(buf+8*j, &hv, &lv);
                U4 H,L; H.v=hv; L.v=lv;
                *(uint4*)&Ah[r*64+seg*32+j*8] = H.q;
                *(uint4*)&Al[r*64+seg*32+j*8] = L.q;
            }
        }
        // B: async global->LDS (rows are n, cols k-chunk)
        for (int c=wave;c<14;c+=4){
            size_t go=(size_t)(c*8+(lane>>3))*512 + (size_t)kc*128 + (size_t)(lane&7)*16;
            gll16((const char*)WT_h+go, Bh+c*512);
            gll16((const char*)WT_l+go, Bl+c*512);
        }
        __syncthreads();

        #pragma unroll
        for (int ks=0;ks<2;++ks){
            bf16x8 ah[2],al[2],bh[7],bl[7];
            #pragma unroll
            for (int mi=0;mi<2;++mi){
                int row=wave*32+mi*16+fr;
                ah[mi]=*(const bf16x8*)&Ah[row*64+ks*32+fq*8];
                al[mi]=*(const bf16x8*)&Al[row*64+ks*32+fq*8];
            }
            #pragma unroll
            for (int ni=0;ni<7;++ni){
                int rowb=ni*16+fr;
                bh[ni]=*(const bf16x8*)&Bh[rowb*64+ks*32+fq*8];
                bl[ni]=*(const bf16x8*)&Bl[rowb*64+ks*32+fq*8];
            }
            #pragma unroll
            for (int mi=0;mi<2;++mi)
                #pragma unroll
                for (int ni=0;ni<7;++ni){
                    acc[mi][ni]=MFMA(ah[mi],bh[ni],acc[mi][ni]);
                    acc[mi][ni]=MFMA(ah[mi],bl[ni],acc[mi][ni]);
                    acc[mi][ni]=MFMA(al[mi],bh[ni],acc[mi][ni]);
                }
        }
    }
    __syncthreads();
    // mlp = tanh(acc + b_att) -> LDS (C/D layout: col=lane&15, row=quad*4+reg)
    #pragma unroll
    for (int ni=0;ni<7;++ni){
        int col=ni*16+fr;
        float bb=(col<100)? b_att[col] : 0.f;
        #pragma unroll
        for (int mi=0;mi<2;++mi){
            int rb=wave*32+mi*16+fq*4;
            #pragma unroll
            for (int r=0;r<4;++r)
                mlp_s[(rb+r)*112+col]=tanhf(acc[mi][ni][r]+bb);
        }
    }
    __syncthreads();
    if (tid<128){
        float s=0.f;
        for (int n=0;n<100;++n) s+=mlp_s[tid*112+n]*s_vatt[n];
        s_pre[tid]=s;
    }
    __syncthreads();
    if (tid<25){    // softmax over L=5
        float p[5], mx=-1e30f;
        #pragma unroll
        for (int l=0;l<5;++l){ p[l]=s_pre[tid*5+l]; mx=fmaxf(mx,p[l]); }
        float s=0.f;
        #pragma unroll
        for (int l=0;l<5;++l){ p[l]=__expf(p[l]-mx); s+=p[l]; }
        float inv=1.f/s;
        #pragma unroll
        for (int l=0;l<5;++l) s_attw[tid*5+l]=p[l]*inv;
    }
    __syncthreads();
    for (int o=tid;o<3200;o+=256){   // emb[v][e] = sum_l att * an (fp32)
        int v=o>>7, e=o&127;
        float s=0.f;
        #pragma unroll
        for (int l=0;l<5;++l)
            s += s_attw[v*5+l]*W_emb[(size_t)s_anc[v*5+l]*128+e];
        emb_f[(size_t)(blockIdx.x*25+v)*128+e]=s;
    }
}

// ---------------------------------------------------------------------------
// Phase 1b: emb fp32 [8000][128] -> transposed bf16 hi/lo [128][8000]
__global__ __launch_bounds__(256,1) void emb_split_kernel(
    const float* __restrict__ emb_f, u16* __restrict__ hiT, u16* __restrict__ loT)
{
    __shared__ float tile[64*128];
    const int tid=threadIdx.x;
    const int vb=blockIdx.x*64;
    for (int i=tid;i<2048;i+=256){
        int row=i>>5, q=i&31;
        *(f32x4*)&tile[row*128+q*4] = *(const f32x4*)&emb_f[(size_t)(vb+row)*128+q*4];
    }
    __syncthreads();
    u32* hw=(u32*)hiT; u32* lw=(u32*)loT;
    for (int o=tid;o<4096;o+=256){
        int e=o>>5, p=o&31;
        float f0=tile[(2*p)*128+e], f1=tile[(2*p+1)*128+e];
        u16 h0,l0,h1,l1; split1(f0,h0,l0); split1(f1,h1,l1);
        size_t base=(size_t)e*4000 + (size_t)(vb>>1) + p;
        hw[base]=(u32)h0|((u32)h1<<16);
        lw[base]=(u32)l0|((u32)l1<<16);
    }
}

// ---------------------------------------------------------------------------
// Phase 2: partials[ks][m][e] = x[m, k-slice] @ emb[k-slice, e]
// M-tile 32, N=128, splitK=5 -> 1000 blocks (4 blocks/CU by 40 KB LDS).
// XOR-swizzled LDS layouts (conflict-free fragment reads with contiguous
// global_load_lds: swizzle lives in the per-lane GLOBAL gather address).
// A fp32 -> bf16 hi/lo in regs; 3-combo MFMA (hh + hl + lh).
// ---------------------------------------------------------------------------
__global__ __launch_bounds__(256,4) void gemm_xemb_kernel(
    const float* __restrict__ x, const u16* __restrict__ bhT, const u16* __restrict__ blT,
    float* __restrict__ partials)
{
    __shared__ __align__(16) float Asf[32*64];    // 8 KB  (chunk c of row r at c^(r&15))
    __shared__ __align__(16) short Bh[128*64];    // 16 KB (chunk c of row r at c^(r&7))
    __shared__ __align__(16) short Bl[128*64];    // 16 KB

    const int tid=threadIdx.x, wave=tid>>6, lane=tid&63;
    const int mt=blockIdx.x%200, ks=blockIdx.x/200;
    const int mbase=mt*32;
    const int k0=ks*1600;

    f32x4 acc[2][2];
    const f32x4 zf={0.f,0.f,0.f,0.f};
    #pragma unroll
    for (int i=0;i<2;++i)
        #pragma unroll
        for (int j=0;j<2;++j) acc[i][j]=zf;

    const char* xb=(const char*)x;
    const char* bhb=(const char*)bhT;
    const char* blb=(const char*)blT;
    const int fr=lane&15, fq=lane>>4;
    const int nbase=wave*32;

    for (int kk=k0; kk<k0+1600; kk+=64){
        __syncthreads();
        // A: 32 rows x 16 chunks = 512 chunks; 8 instrs, 2 per wave
        #pragma unroll
        for (int ii=0;ii<2;++ii){
            int L=(wave*2+ii)*64+lane;
            int r=L>>4, c=(L&15)^(r&15);
            gll16(xb + ((size_t)(mbase+r)*8000 + kk + c*4)*4, (char*)Asf + (size_t)L*16);
        }
        // B: 128 rows x 8 chunks = 1024 chunks; 16 instrs each, 4 per wave
        #pragma unroll
        for (int ii=0;ii<4;++ii){
            int L=(wave*4+ii)*64+lane;
            int r=L>>3, c=(L&7)^(r&7);
            size_t go=((size_t)r*8000 + kk + c*8)*2;
            gll16(bhb+go, (char*)Bh + (size_t)L*16);
            gll16(blb+go, (char*)Bl + (size_t)L*16);
        }
        __syncthreads();

        #pragma unroll
        for (int kh=0;kh<2;++kh){
            bf16x8 ah[2],al[2],bh[2],bl[2];
            #pragma unroll
            for (int mi=0;mi<2;++mi){
                int row=mi*16+fr;
                int c0=kh*8+fq*2;
                float buf[8];
                *(f32x4*)&buf[0]=*(const f32x4*)&Asf[(row*16+((c0  )^(row&15)))*4];
                *(f32x4*)&buf[4]=*(const f32x4*)&Asf[(row*16+((c0+1)^(row&15)))*4];
                split8(buf,&ah[mi],&al[mi]);
            }
            #pragma unroll
            for (int ni=0;ni<2;++ni){
                int rowb=nbase+ni*16+fr;
                int ch=rowb*8+((kh*4+fq)^(rowb&7));
                bh[ni]=*(const bf16x8*)&Bh[ch*8];
                bl[ni]=*(const bf16x8*)&Bl[ch*8];
            }
            #pragma unroll
            for (int mi=0;mi<2;++mi)
                #pragma unroll
                for (int ni=0;ni<2;++ni){
                    acc[mi][ni]=MFMA(ah[mi],bh[ni],acc[mi][ni]);
                    acc[mi][ni]=MFMA(ah[mi],bl[ni],acc[mi][ni]);
                    acc[mi][ni]=MFMA(al[mi],bh[ni],acc[mi][ni]);
                }
        }
    }

    float* pout=partials + ((size_t)ks*6400+mbase)*128;
    #pragma unroll
    for (int mi=0;mi<2;++mi)
        #pragma unroll
        for (int ni=0;ni<2;++ni)
            #pragma unroll
            for (int r=0;r<4;++r)
                pout[(size_t)(mi*16+fq*4+r)*128 + nbase+ni*16+fr]=acc[mi][ni][r];
}

// Phase 2b: x_emb = tanh(sum over 5 K-split partials)
__global__ __launch_bounds__(256,1) void sum_tanh_kernel(
    const float* __restrict__ partials, float* __restrict__ x_emb)
{
    int i=blockIdx.x*256+threadIdx.x;             // < 819200
    float s=0.f;
    #pragma unroll
    for (int k=0;k<5;++k) s+=partials[(size_t)k*819200+i];
    x_emb[i]=tanhf(s);
}

// ---------------------------------------------------------------------------
// Phase 3a: GX[m][j] = x_emb[m,:] @ w_ih[j,:] + b_ih[j]
__global__ __launch_bounds__(128,1) void gx_gemm_kernel(
    const float* __restrict__ x_emb, const float* __restrict__ w_ihT,
    const float* __restrict__ b_ih, float* __restrict__ GX)
{
    __shared__ float sx[2048];
    const int tid=threadIdx.x;
    const int rb=blockIdx.x*16;
    for (int i=tid;i<2048;i+=128) sx[i]=x_emb[(size_t)rb*128+i];
    __syncthreads();

    float acc0[16],acc1[16],acc2[16];
    #pragma unroll
    for (int r=0;r<16;++r){ acc0[r]=0.f; acc1[r]=0.f; acc2[r]=0.f; }
    for (int e=0;e<128;++e){
        float w0=w_ihT[e*384+tid];
        float w1=w_ihT[e*384+tid+128];
        float w2=w_ihT[e*384+tid+256];
        #pragma unroll
        for (int r=0;r<16;++r){
            float xv=sx[r*128+e];
            acc0[r]=fmaf(xv,w0,acc0[r]);
            acc1[r]=fmaf(xv,w1,acc1[r]);
            acc2[r]=fmaf(xv,w2,acc2[r]);
        }
    }
    float b0=b_ih[tid], b1=b_ih[tid+128], b2=b_ih[tid+256];
    #pragma unroll
    for (int r=0;r<16;++r){
        float* gp=GX+(size_t)(rb+r)*384;
        gp[tid]=acc0[r]+b0;
        gp[tid+128]=acc1[r]+b1;
        gp[tid+256]=acc2[r]+b2;
    }
}

// ---------------------------------------------------------------------------
// Phase 3b: GRU scan, one block per batch element.
// w_hh pre-unpacked to 128 fp32 VGPRs; h stored bf16 in LDS (16 b128/thread/step);
// h_prev kept in register; GX loaded direct-to-register by tid<128.
// ---------------------------------------------------------------------------
__global__ __launch_bounds__(384,1) void gru_scan_kernel(
    const u32* __restrict__ whh_p, const float* __restrict__ b_hh,
    const float* __restrict__ GX, float* __restrict__ hidden)
{
    __shared__ __align__(16) u16 shb[128];   // h as bf16
    __shared__ float sgh[384];
    const int tid=threadIdx.x, b=blockIdx.x;

    float wf[128];
    #pragma unroll
    for (int q=0;q<64;++q){
        u32 u=whh_p[tid*64+q];
        wf[2*q]  =uaf(u<<16);
        wf[2*q+1]=uaf(u&0xffff0000u);
    }
    float hreg=0.f;
    if (tid<128) shb[tid]=0;
    const float bb=b_hh[tid];
    __syncthreads();

    for (int t=0;t<50;++t){
        float gx0=0.f,gx1=0.f,gx2=0.f;
        if (tid<128){
            const float* gp=GX+((size_t)t*128+b)*384;
            gx0=gp[tid]; gx1=gp[128+tid]; gx2=gp[256+tid];
        }
        float acc=0.f;
        #pragma unroll
        for (int p=0;p<16;++p){
            U4 c; c.v=*(const bf16x8*)&shb[p*8];
            #pragma unroll
            for (int j=0;j<4;++j){
                u32 u=c.u[j];
                acc=fmaf(uaf(u<<16),         wf[p*8+2*j],   acc);
                acc=fmaf(uaf(u&0xffff0000u), wf[p*8+2*j+1], acc);
            }
        }
        sgh[tid]=acc+bb;
        __syncthreads();
        if (tid<128){
            float r=sigm(gx0+sgh[tid]);
            float z=sigm(gx1+sgh[128+tid]);
            float n=tanhf(gx2+r*sgh[256+tid]);
            float hn=(1.f-z)*n+z*hreg;
            hreg=hn;
            hidden[((size_t)t*128+b)*128+tid]=hn;
            shb[tid]=f2bf(hn);
        }
        __syncthreads();
    }
}

// ---------------------------------------------------------------------------
// Phase 4a: logits[m][c] = hidden[m,:] @ W_out[:,c] + b_out[c]
__global__ __launch_bounds__(128,1) void logits_kernel(
    const float* __restrict__ hidden, const float* __restrict__ W_out,
    const float* __restrict__ b_out, float* __restrict__ logits)
{
    __shared__ float shd[2048];
    const int tid=threadIdx.x;
    const int rb=blockIdx.x*16;
    for (int i=tid;i<2048;i+=128) shd[i]=hidden[(size_t)rb*128+i];
    __syncthreads();

    const int c0=tid, c1=tid+128, c2=tid+256;
    const bool v2=(c2<283);
    float acc0[16],acc1[16],acc2[16];
    #pragma unroll
    for (int r=0;r<16;++r){ acc0[r]=0.f; acc1[r]=0.f; acc2[r]=0.f; }
    for (int h=0;h<128;++h){
        const float* wr=W_out+h*283;
        float w0=wr[c0];
        float w1=wr[c1];
        float w2=v2? wr[c2] : 0.f;
        #pragma unroll
        for (int r=0;r<16;++r){
            float hv=shd[r*128+h];
            acc0[r]=fmaf(hv,w0,acc0[r]);
            acc1[r]=fmaf(hv,w1,acc1[r]);
            acc2[r]=fmaf(hv,w2,acc2[r]);
        }
    }
    float b0=b_out[c0], b1=b_out[c1], b2v=v2? b_out[c2] : 0.f;
    #pragma unroll
    for (int r=0;r<16;++r){
        float* lp=logits+(size_t)(rb+r)*283;
        lp[c0]=acc0[r]+b0;
        lp[c1]=acc1[r]+b1;
        if (v2) lp[c2]=acc2[r]+b2v;
    }
}

// Phase 4b: row softmax over C=283, * mask, write fp32. One wave per row.
__global__ __launch_bounds__(256,1) void softmax_mask_kernel(
    const float* __restrict__ logits, const float* __restrict__ mask,
    float* __restrict__ out)
{
    const int wave=threadIdx.x>>6, lane=threadIdx.x&63;
    const int m=blockIdx.x*4+wave;                 // < 6400
    const float* lp=logits+(size_t)m*283;
    float v[5];
    float mx=-1e30f;
    #pragma unroll
    for (int i=0;i<5;++i){
        int c=lane+i*64;
        v[i]=(c<283)? lp[c] : -1e30f;
        mx=fmaxf(mx,v[i]);
    }
    #pragma unroll
    for (int off=32;off>0;off>>=1) mx=fmaxf(mx,__shfl_xor(mx,off,64));
    float s=0.f;
    #pragma unroll
    for (int i=0;i<5;++i){
        int c=lane+i*64;
        v[i]=(c<283)? __expf(v[i]-mx) : 0.f;
        s+=v[i];
    }
    #pragma unroll
    for (int off=32;off>0;off>>=1) s+=__shfl_xor(s,off,64);
    const float sc=mask[m]/s;
    float* op=out+(size_t)m*283;
    #pragma unroll
    for (int i=0;i<5;++i){
        int c=lane+i*64;
        if (c<283) op[c]=v[i]*sc;
    }
}

// ---------------------------------------------------------------------------
extern "C" void kernel_launch(void* const* d_in, const int* in_sizes, int n_in,
                              void* d_out, int out_size, void* d_ws, size_t ws_size,
                              hipStream_t stream) {
    const float* x      = (const float*)d_in[0];    // [50,128,8000]
    const float* mask   = (const float*)d_in[1];    // [50,128]
    const float* W_emb  = (const float*)d_in[2];    // [8728,128]
    const float* W_att  = (const float*)d_in[3];    // [256,100]
    const float* b_att  = (const float*)d_in[4];    // [100]
    const float* v_att  = (const float*)d_in[5];    // [100]
    const float* w_ih   = (const float*)d_in[6];    // [384,128]
    const float* w_hh   = (const float*)d_in[7];    // [384,128]
    const float* b_ih   = (const float*)d_in[8];    // [384]
    const float* b_hh   = (const float*)d_in[9];    // [384]
    const float* W_out  = (const float*)d_in[10];   // [128,283]
    const float* b_out  = (const float*)d_in[11];   // [283]
    const int* leaves   = (const int*)d_in[12];     // [8000,5]
    const int* anc      = (const int*)d_in[13];     // [8000,5]
    float* out = (float*)d_out;                     // [50,128,283] fp32

    char* w = (char*)d_ws;
    u16*   WT_h    = (u16*)(w + 0);                 //    57,344
    u16*   WT_l    = (u16*)(w + 57344);             //    57,344
    u32*   whh_p   = (u32*)(w + 114688);            //    98,304
    float* w_ihT   = (float*)(w + 212992);          //   196,608
    u16*   emb_hiT = (u16*)(w + 409600);            // 2,048,000
    u16*   emb_loT = (u16*)(w + 2457600);           // 2,048,000
    float* x_emb   = (float*)(w + 4505600);         // 3,276,800
    float* hidden  = (float*)(w + 7782400);         // 3,276,800
    // overlay @ 11,059,200 (16,384,000 B): emb_f32 -> partials -> GX -> logits
    float* emb_f   = (float*)(w + 11059200);        // 4,096,000 (dead after emb_split)
    float* partials= (float*)(w + 11059200);        // [5][6400][128] f32
    float* GX      = (float*)(w + 11059200);        // [6400][384] f32
    float* logits  = (float*)(w + 11059200);        // [6400][283] f32

    prep_watt_kernel<<<112, 256, 0, stream>>>(W_att, WT_h, WT_l);
    prep_whh_kernel<<<96, 256, 0, stream>>>(w_hh, whh_p);
    transpose_wih_kernel<<<192, 256, 0, stream>>>(w_ih, w_ihT);
    attn_mlp_kernel<<<320, 256, 0, stream>>>(W_emb, b_att, v_att, leaves, anc,
                                             WT_h, WT_l, emb_f);
    emb_split_kernel<<<125, 256, 0, stream>>>(emb_f, emb_hiT, emb_loT);
    gemm_xemb_kernel<<<1000, 256, 0, stream>>>(x, emb_hiT, emb_loT, partials);
    sum_tanh_kernel<<<3200, 256, 0, stream>>>(partials, x_emb);
    gx_gemm_kernel<<<400, 128, 0, stream>>>(x_emb, w_ihT, b_ih, GX);
    gru_scan_kernel<<<128, 384, 0, stream>>>(whh_p, b_hh, GX, hidden);
    logits_kernel<<<400, 128, 0, stream>>>(hidden, W_out, b_out, logits);
    softmax_mask_kernel<<<1600, 256, 0, stream>>>(logits, mask, out);
}

// Round 5
// 523.686 us; speedup vs baseline: 1.0499x; 1.0106x over previous
//
#include <hip/hip_runtime.h>

// GRAM model: ontology attention (MFMA) -> embedding projection (MFMA) -> GRU -> softmax
// Sizes: T=50 B=128 V=8000 NEMB=8728 E=128 H=128 ATT=100 C=283 L=5, M=T*B=6400
// dtypes: float tensors fp32 (inputs AND output); leaves/ancestors int32.

typedef unsigned short u16;
typedef unsigned int   u32;
typedef short bf16x8 __attribute__((ext_vector_type(8)));
typedef float f32x4  __attribute__((ext_vector_type(4)));

typedef __attribute__((address_space(1))) u32 gas_u32;
typedef __attribute__((address_space(3))) u32 las_u32;

union U4 { u32 u[4]; bf16x8 v; uint4 q; };

__device__ __forceinline__ float uaf(u32 u){ union{u32 u; float f;} c; c.u=u; return c.f; }
__device__ __forceinline__ u32 fau(float f){ union{u32 u; float f;} c; c.f=f; return c.u; }
__device__ __forceinline__ u16 f2bf(float f){ u32 u=fau(f); return (u16)((u + 0x7fffu + ((u>>16)&1u))>>16); }
__device__ __forceinline__ float sigm(float x){ return 1.f/(1.f+__expf(-x)); }

__device__ __forceinline__ void gll16(const void* g, void* l){
    __builtin_amdgcn_global_load_lds((const gas_u32*)g, (las_u32*)l, 16, 0, 0);
}

// split 8 consecutive floats into bf16-hi and bf16-lo packed fragments (RNE)
__device__ __forceinline__ void split8(const float* f, bf16x8* hi, bf16x8* lo){
    U4 H, L;
    #pragma unroll
    for (int j=0;j<4;++j){
        float f0=f[2*j], f1=f[2*j+1];
        u32 u0=fau(f0), u1=fau(f1);
        u32 t0=u0+0x7fffu+((u0>>16)&1u);
        u32 t1=u1+0x7fffu+((u1>>16)&1u);
        u32 h1=t1&0xffff0000u;
        H.u[j]=(t0>>16)|h1;
        float l0=f0-uaf(t0&0xffff0000u);
        float l1=f1-uaf(h1);
        u32 v0=fau(l0), v1=fau(l1);
        u32 s0=v0+0x7fffu+((v0>>16)&1u);
        u32 s1=v1+0x7fffu+((v1>>16)&1u);
        L.u[j]=(s0>>16)|(s1&0xffff0000u);
    }
    *hi=H.v; *lo=L.v;
}

__device__ __forceinline__ void split1(float f, u16& h, u16& l){
    u32 u=fau(f); u32 t=u+0x7fffu+((u>>16)&1u); h=(u16)(t>>16);
    float lf=f-uaf(t&0xffff0000u); l=f2bf(lf);
}

#define MFMA(a,b,c) __builtin_amdgcn_mfma_f32_16x16x32_bf16(a,b,c,0,0,0)

// ---------------------------------------------------------------------------
// prep: W_att [256][100] fp32 -> WT_h/WT_l [112][256] bf16 (rows >=100 zero)
__global__ __launch_bounds__(256,1) void prep_watt_kernel(
    const float* __restrict__ W_att, u16* __restrict__ WT_h, u16* __restrict__ WT_l)
{
    int n=blockIdx.x, k=threadIdx.x;          // n<112, k<256
    float f = (n<100)? W_att[k*100+n] : 0.f;
    u16 h,l; split1(f,h,l);
    WT_h[n*256+k]=h; WT_l[n*256+k]=l;
}

// prep: w_hh [384][128] fp32 -> bf16 pairs u32[384*64]
__global__ __launch_bounds__(256,1) void prep_whh_kernel(
    const float* __restrict__ whh, u32* __restrict__ out)
{
    int i=blockIdx.x*256+threadIdx.x;         // < 24576
    int j=i>>6, p=i&63;
    u32 a=(u32)f2bf(whh[j*128+2*p]);
    u32 b=(u32)f2bf(whh[j*128+2*p+1]);
    out[i]=a|(b<<16);
}

// prep: w_ihT[e][j] = w_ih[j][e] fp32
__global__ __launch_bounds__(256,1) void transpose_wih_kernel(
    const float* __restrict__ w_ih, float* __restrict__ w_ihT)
{
    int i=blockIdx.x*256+threadIdx.x;         // < 49152
    int e=i/384, j=i-e*384;
    w_ihT[i]=w_ih[j*128+e];
}

// ---------------------------------------------------------------------------
// Phase 1: attention MLP via MFMA + softmax over L + emb reduce (fp32).
// One block = 25 leaf codes = 125 (v,l) rows (pad to 128). N=112 (100 used), K=256.
// ---------------------------------------------------------------------------
__global__ __launch_bounds__(256,1) void attn_mlp_kernel(
    const float* __restrict__ W_emb, const float* __restrict__ b_att,
    const float* __restrict__ v_att, const int* __restrict__ leaves,
    const int* __restrict__ anc, const u16* __restrict__ WT_h,
    const u16* __restrict__ WT_l, float* __restrict__ emb_f)
{
    __shared__ __align__(16) char smem[61440];
    short* Ah=(short*)smem;                 // [128][64] bf16  16384 B
    short* Al=(short*)(smem+16384);         // 16384 B
    short* Bh=(short*)(smem+32768);         // [112][64] 14336 B
    short* Bl=(short*)(smem+47104);         // 14336 B
    float* mlp_s=(float*)smem;              // [128][112] fp32 (after MFMA, 57344 B)
    __shared__ float s_pre[128];
    __shared__ float s_vatt[112];
    __shared__ float s_attw[128];
    __shared__ int   s_leaf[128], s_anc[128];

    const int tid=threadIdx.x;
    const int wave=tid>>6, lane=tid&63;
    const int vb5=blockIdx.x*125;           // first (v,l) flat row

    if (tid<125){ s_leaf[tid]=leaves[vb5+tid]; s_anc[tid]=anc[vb5+tid]; }
    else if (tid<128){ s_leaf[tid]=leaves[vb5]; s_anc[tid]=anc[vb5]; }
    if (tid<100) s_vatt[tid]=v_att[tid];

    f32x4 acc[2][7];
    const f32x4 zf={0.f,0.f,0.f,0.f};
    #pragma unroll
    for (int mi=0;mi<2;++mi)
        #pragma unroll
        for (int ni=0;ni<7;++ni) acc[mi][ni]=zf;

    const int fr=lane&15, fq=lane>>4;

    for (int kc=0;kc<4;++kc){               // K chunks of 64: 0,1=leaf half, 2,3=anc half
        __syncthreads();
        {   // A: gather + hi/lo split; thread -> (row r=tid>>1, seg=tid&1: 32 floats)
            int r=tid>>1, seg=tid&1;
            int src=(kc<2)? s_leaf[r] : s_anc[r];
            const float* srcp = W_emb + (size_t)src*128 + (kc&1)*64 + seg*32;
            float buf[32];
            #pragma unroll
            for (int i=0;i<8;++i) *(f32x4*)(buf+4*i) = *(const f32x4*)(srcp+4*i);
            #pragma unroll
            for (int j=0;j<4;++j){
                bf16x8 hv, lv; split8(buf+8*j, &hv, &lv);
                U4 H,L; H.v=hv; L.v=lv;
                *(uint4*)&Ah[r*64+seg*32+j*8] = H.q;
                *(uint4*)&Al[r*64+seg*32+j*8] = L.q;
            }
        }
        // B: async global->LDS (rows are n, cols k-chunk)
        for (int c=wave;c<14;c+=4){
            size_t go=(size_t)(c*8+(lane>>3))*512 + (size_t)kc*128 + (size_t)(lane&7)*16;
            gll16((const char*)WT_h+go, Bh+c*512);
            gll16((const char*)WT_l+go, Bl+c*512);
        }
        __syncthreads();

        #pragma unroll
        for (int ks=0;ks<2;++ks){
            bf16x8 ah[2],al[2],bh[7],bl[7];
            #pragma unroll
            for (int mi=0;mi<2;++mi){
                int row=wave*32+mi*16+fr;
                ah[mi]=*(const bf16x8*)&Ah[row*64+ks*32+fq*8];
                al[mi]=*(const bf16x8*)&Al[row*64+ks*32+fq*8];
            }
            #pragma unroll
            for (int ni=0;ni<7;++ni){
                int rowb=ni*16+fr;
                bh[ni]=*(const bf16x8*)&Bh[rowb*64+ks*32+fq*8];
                bl[ni]=*(const bf16x8*)&Bl[rowb*64+ks*32+fq*8];
            }
            #pragma unroll
            for (int mi=0;mi<2;++mi)
                #pragma unroll
                for (int ni=0;ni<7;++ni){
                    acc[mi][ni]=MFMA(ah[mi],bh[ni],acc[mi][ni]);
                    acc[mi][ni]=MFMA(ah[mi],bl[ni],acc[mi][ni]);
                    acc[mi][ni]=MFMA(al[mi],bh[ni],acc[mi][ni]);
                }
        }
    }
    __syncthreads();
    // mlp = tanh(acc + b_att) -> LDS (C/D layout: col=lane&15, row=quad*4+reg)
    #pragma unroll
    for (int ni=0;ni<7;++ni){
        int col=ni*16+fr;
        float bb=(col<100)? b_att[col] : 0.f;
        #pragma unroll
        for (int mi=0;mi<2;++mi){
            int rb=wave*32+mi*16+fq*4;
            #pragma unroll
            for (int r=0;r<4;++r)
                mlp_s[(rb+r)*112+col]=tanhf(acc[mi][ni][r]+bb);
        }
    }
    __syncthreads();
    if (tid<128){
        float s=0.f;
        for (int n=0;n<100;++n) s+=mlp_s[tid*112+n]*s_vatt[n];
        s_pre[tid]=s;
    }
    __syncthreads();
    if (tid<25){    // softmax over L=5
        float p[5], mx=-1e30f;
        #pragma unroll
        for (int l=0;l<5;++l){ p[l]=s_pre[tid*5+l]; mx=fmaxf(mx,p[l]); }
        float s=0.f;
        #pragma unroll
        for (int l=0;l<5;++l){ p[l]=__expf(p[l]-mx); s+=p[l]; }
        float inv=1.f/s;
        #pragma unroll
        for (int l=0;l<5;++l) s_attw[tid*5+l]=p[l]*inv;
    }
    __syncthreads();
    for (int o=tid;o<3200;o+=256){   // emb[v][e] = sum_l att * an (fp32)
        int v=o>>7, e=o&127;
        float s=0.f;
        #pragma unroll
        for (int l=0;l<5;++l)
            s += s_attw[v*5+l]*W_emb[(size_t)s_anc[v*5+l]*128+e];
        emb_f[(size_t)(blockIdx.x*25+v)*128+e]=s;
    }
}

// ---------------------------------------------------------------------------
// Phase 1b: emb fp32 [8000][128] -> transposed bf16 hi/lo [128][8000]
__global__ __launch_bounds__(256,1) void emb_split_kernel(
    const float* __restrict__ emb_f, u16* __restrict__ hiT, u16* __restrict__ loT)
{
    __shared__ float tile[64*128];
    const int tid=threadIdx.x;
    const int vb=blockIdx.x*64;
    for (int i=tid;i<2048;i+=256){
        int row=i>>5, q=i&31;
        *(f32x4*)&tile[row*128+q*4] = *(const f32x4*)&emb_f[(size_t)(vb+row)*128+q*4];
    }
    __syncthreads();
    u32* hw=(u32*)hiT; u32* lw=(u32*)loT;
    for (int o=tid;o<4096;o+=256){
        int e=o>>5, p=o&31;
        float f0=tile[(2*p)*128+e], f1=tile[(2*p+1)*128+e];
        u16 h0,l0,h1,l1; split1(f0,h0,l0); split1(f1,h1,l1);
        size_t base=(size_t)e*4000 + (size_t)(vb>>1) + p;
        hw[base]=(u32)h0|((u32)h1<<16);
        lw[base]=(u32)l0|((u32)l1<<16);
    }
}

// ---------------------------------------------------------------------------
// Phase 2: partials[ks][m][e] = x[m, k-slice] @ emb[k-slice, e]
// M-tile 32, N=128, splitK=5 -> 1000 blocks (4 blocks/CU by 40 KB LDS).
// XOR swizzle lives ONLY in the per-lane GLOBAL address; LDS dest passed as
// the wave-uniform base (hardware scatters lane*16) — m97-proven codegen path.
// A fp32 -> bf16 hi/lo in regs; 3-combo MFMA (hh + hl + lh).
// ---------------------------------------------------------------------------
__global__ __launch_bounds__(256,4) void gemm_xemb_kernel(
    const float* __restrict__ x, const u16* __restrict__ bhT, const u16* __restrict__ blT,
    float* __restrict__ partials)
{
    __shared__ __align__(16) float Asf[32*64];    // 8 KB  (chunk c of row r at c^(r&15))
    __shared__ __align__(16) short Bh[128*64];    // 16 KB (chunk c of row r at c^(r&7))
    __shared__ __align__(16) short Bl[128*64];    // 16 KB

    const int tid=threadIdx.x, wave=tid>>6, lane=tid&63;
    const int mt=blockIdx.x%200, ks=blockIdx.x/200;
    const int mbase=mt*32;
    const int k0=ks*1600;

    f32x4 acc[2][2];
    const f32x4 zf={0.f,0.f,0.f,0.f};
    #pragma unroll
    for (int i=0;i<2;++i)
        #pragma unroll
        for (int j=0;j<2;++j) acc[i][j]=zf;

    const char* xb=(const char*)x;
    const char* bhb=(const char*)bhT;
    const char* blb=(const char*)blT;
    const int fr=lane&15, fq=lane>>4;
    const int nbase=wave*32;

    // per-lane (row, swizzled-chunk) for the staging instructions
    const int ar = lane>>4;                 // A: 4 rows per instr
    const int ac0 = lane&15;                // logical chunk within row (pre-swizzle)
    const int br = lane>>3;                 // B: 8 rows per instr
    const int bc0 = lane&7;

    for (int kk=k0; kk<k0+1600; kk+=64){
        __syncthreads();
        // A: 32 rows x 16 chunks(4 floats); 8 instrs (2/wave), uniform LDS base
        #pragma unroll
        for (int ii=0;ii<2;++ii){
            int t=wave*2+ii;
            int r=t*4+ar;
            int c=ac0^(r&15);
            gll16(xb + ((size_t)(mbase+r)*8000 + kk + c*4)*4,
                  (char*)Asf + (size_t)t*1024);
        }
        // B: 128 rows x 8 chunks(8 shorts); 16 instrs each array (4/wave)
        #pragma unroll
        for (int ii=0;ii<4;++ii){
            int s=wave*4+ii;
            int r=s*8+br;
            int c=bc0^(r&7);
            size_t go=((size_t)r*8000 + kk + c*8)*2;
            gll16(bhb+go, (char*)Bh + (size_t)s*1024);
            gll16(blb+go, (char*)Bl + (size_t)s*1024);
        }
        __syncthreads();

        #pragma unroll
        for (int kh=0;kh<2;++kh){
            bf16x8 ah[2],al[2],bh[2],bl[2];
            #pragma unroll
            for (int mi=0;mi<2;++mi){
                int row=mi*16+fr;
                int c0=kh*8+fq*2;
                float buf[8];
                *(f32x4*)&buf[0]=*(const f32x4*)&Asf[(row*16+((c0  )^(row&15)))*4];
                *(f32x4*)&buf[4]=*(const f32x4*)&Asf[(row*16+((c0+1)^(row&15)))*4];
                split8(buf,&ah[mi],&al[mi]);
            }
            #pragma unroll
            for (int ni=0;ni<2;++ni){
                int rowb=nbase+ni*16+fr;
                int ch=rowb*8+((kh*4+fq)^(rowb&7));
                bh[ni]=*(const bf16x8*)&Bh[ch*8];
                bl[ni]=*(const bf16x8*)&Bl[ch*8];
            }
            #pragma unroll
            for (int mi=0;mi<2;++mi)
                #pragma unroll
                for (int ni=0;ni<2;++ni){
                    acc[mi][ni]=MFMA(ah[mi],bh[ni],acc[mi][ni]);
                    acc[mi][ni]=MFMA(ah[mi],bl[ni],acc[mi][ni]);
                    acc[mi][ni]=MFMA(al[mi],bh[ni],acc[mi][ni]);
                }
        }
    }

    float* pout=partials + ((size_t)ks*6400+mbase)*128;
    #pragma unroll
    for (int mi=0;mi<2;++mi)
        #pragma unroll
        for (int ni=0;ni<2;++ni)
            #pragma unroll
            for (int r=0;r<4;++r)
                pout[(size_t)(mi*16+fq*4+r)*128 + nbase+ni*16+fr]=acc[mi][ni][r];
}

// ---------------------------------------------------------------------------
// Phase 2b+3a fused: x_emb = tanh(sum partials); GX = x_emb @ w_ih^T + b_ih
__global__ __launch_bounds__(128,1) void sumtanh_gx_kernel(
    const float* __restrict__ partials, const float* __restrict__ w_ihT,
    const float* __restrict__ b_ih, float* __restrict__ GX)
{
    __shared__ float sx[2048];
    const int tid=threadIdx.x;
    const int rb=blockIdx.x*16;
    for (int i=tid;i<2048;i+=128){
        size_t o=(size_t)rb*128+i;
        float s=0.f;
        #pragma unroll
        for (int k=0;k<5;++k) s+=partials[(size_t)k*819200+o];
        sx[i]=tanhf(s);
    }
    __syncthreads();

    float acc0[16],acc1[16],acc2[16];
    #pragma unroll
    for (int r=0;r<16;++r){ acc0[r]=0.f; acc1[r]=0.f; acc2[r]=0.f; }
    for (int e=0;e<128;++e){
        float w0=w_ihT[e*384+tid];
        float w1=w_ihT[e*384+tid+128];
        float w2=w_ihT[e*384+tid+256];
        #pragma unroll
        for (int r=0;r<16;++r){
            float xv=sx[r*128+e];
            acc0[r]=fmaf(xv,w0,acc0[r]);
            acc1[r]=fmaf(xv,w1,acc1[r]);
            acc2[r]=fmaf(xv,w2,acc2[r]);
        }
    }
    float b0=b_ih[tid], b1=b_ih[tid+128], b2=b_ih[tid+256];
    #pragma unroll
    for (int r=0;r<16;++r){
        float* gp=GX+(size_t)(rb+r)*384;
        gp[tid]=acc0[r]+b0;
        gp[tid+128]=acc1[r]+b1;
        gp[tid+256]=acc2[r]+b2;
    }
}

// ---------------------------------------------------------------------------
// Phase 3b: GRU scan, one block per batch element.
// w_hh pre-unpacked to 128 fp32 VGPRs; h stored bf16 in LDS; h_prev in register.
// ---------------------------------------------------------------------------
__global__ __launch_bounds__(384,1) void gru_scan_kernel(
    const u32* __restrict__ whh_p, const float* __restrict__ b_hh,
    const float* __restrict__ GX, float* __restrict__ hidden)
{
    __shared__ __align__(16) u16 shb[128];   // h as bf16
    __shared__ float sgh[384];
    const int tid=threadIdx.x, b=blockIdx.x;

    float wf[128];
    #pragma unroll
    for (int q=0;q<64;++q){
        u32 u=whh_p[tid*64+q];
        wf[2*q]  =uaf(u<<16);
        wf[2*q+1]=uaf(u&0xffff0000u);
    }
    float hreg=0.f;
    if (tid<128) shb[tid]=0;
    const float bb=b_hh[tid];
    __syncthreads();

    for (int t=0;t<50;++t){
        float gx0=0.f,gx1=0.f,gx2=0.f;
        if (tid<128){
            const float* gp=GX+((size_t)t*128+b)*384;
            gx0=gp[tid]; gx1=gp[128+tid]; gx2=gp[256+tid];
        }
        float acc=0.f;
        #pragma unroll
        for (int p=0;p<16;++p){
            U4 c; c.v=*(const bf16x8*)&shb[p*8];
            #pragma unroll
            for (int j=0;j<4;++j){
                u32 u=c.u[j];
                acc=fmaf(uaf(u<<16),         wf[p*8+2*j],   acc);
                acc=fmaf(uaf(u&0xffff0000u), wf[p*8+2*j+1], acc);
            }
        }
        sgh[tid]=acc+bb;
        __syncthreads();
        if (tid<128){
            float r=sigm(gx0+sgh[tid]);
            float z=sigm(gx1+sgh[128+tid]);
            float n=tanhf(gx2+r*sgh[256+tid]);
            float hn=(1.f-z)*n+z*hreg;
            hreg=hn;
            hidden[((size_t)t*128+b)*128+tid]=hn;
            shb[tid]=f2bf(hn);
        }
        __syncthreads();
    }
}

// ---------------------------------------------------------------------------
// Phase 4 fused: logits (LDS) -> row softmax -> * mask -> out. 16 rows/block.
__global__ __launch_bounds__(128,1) void logits_softmax_kernel(
    const float* __restrict__ hidden, const float* __restrict__ W_out,
    const float* __restrict__ b_out, const float* __restrict__ mask,
    float* __restrict__ out)
{
    __shared__ float shd[2048];
    __shared__ float slog[16*288];
    const int tid=threadIdx.x;
    const int rb=blockIdx.x*16;
    for (int i=tid;i<2048;i+=128) shd[i]=hidden[(size_t)rb*128+i];
    __syncthreads();

    const int c0=tid, c1=tid+128, c2=tid+256;
    const bool v2=(c2<283);
    float acc0[16],acc1[16],acc2[16];
    #pragma unroll
    for (int r=0;r<16;++r){ acc0[r]=0.f; acc1[r]=0.f; acc2[r]=0.f; }
    for (int h=0;h<128;++h){
        const float* wr=W_out+h*283;
        float w0=wr[c0];
        float w1=wr[c1];
        float w2=v2? wr[c2] : 0.f;
        #pragma unroll
        for (int r=0;r<16;++r){
            float hv=shd[r*128+h];
            acc0[r]=fmaf(hv,w0,acc0[r]);
            acc1[r]=fmaf(hv,w1,acc1[r]);
            acc2[r]=fmaf(hv,w2,acc2[r]);
        }
    }
    float b0=b_out[c0], b1=b_out[c1], b2v=v2? b_out[c2] : 0.f;
    #pragma unroll
    for (int r=0;r<16;++r){
        slog[r*288+c0]=acc0[r]+b0;
        slog[r*288+c1]=acc1[r]+b1;
        if (v2) slog[r*288+c2]=acc2[r]+b2v;
    }
    __syncthreads();

    // softmax: wave wv handles rows wv*8 .. wv*8+7 (one wave per row-pass)
    const int wv=tid>>6, lane=tid&63;
    #pragma unroll
    for (int rr=0;rr<8;++rr){
        int r=wv*8+rr;
        int m=rb+r;
        float v[5];
        float mx=-1e30f;
        #pragma unroll
        for (int i=0;i<5;++i){
            int c=lane+i*64;
            v[i]=(c<283)? slog[r*288+c] : -1e30f;
            mx=fmaxf(mx,v[i]);
        }
        #pragma unroll
        for (int off=32;off>0;off>>=1) mx=fmaxf(mx,__shfl_xor(mx,off,64));
        float s=0.f;
        #pragma unroll
        for (int i=0;i<5;++i){
            int c=lane+i*64;
            v[i]=(c<283)? __expf(v[i]-mx) : 0.f;
            s+=v[i];
        }
        #pragma unroll
        for (int off=32;off>0;off>>=1) s+=__shfl_xor(s,off,64);
        const float sc=mask[m]/s;
        float* op=out+(size_t)m*283;
        #pragma unroll
        for (int i=0;i<5;++i){
            int c=lane+i*64;
            if (c<283) op[c]=v[i]*sc;
        }
    }
}

// ---------------------------------------------------------------------------
extern "C" void kernel_launch(void* const* d_in, const int* in_sizes, int n_in,
                              void* d_out, int out_size, void* d_ws, size_t ws_size,
                              hipStream_t stream) {
    const float* x      = (const float*)d_in[0];    // [50,128,8000]
    const float* mask   = (const float*)d_in[1];    // [50,128]
    const float* W_emb  = (const float*)d_in[2];    // [8728,128]
    const float* W_att  = (const float*)d_in[3];    // [256,100]
    const float* b_att  = (const float*)d_in[4];    // [100]
    const float* v_att  = (const float*)d_in[5];    // [100]
    const float* w_ih   = (const float*)d_in[6];    // [384,128]
    const float* w_hh   = (const float*)d_in[7];    // [384,128]
    const float* b_ih   = (const float*)d_in[8];    // [384]
    const float* b_hh   = (const float*)d_in[9];    // [384]
    const float* W_out  = (const float*)d_in[10];   // [128,283]
    const float* b_out  = (const float*)d_in[11];   // [283]
    const int* leaves   = (const int*)d_in[12];     // [8000,5]
    const int* anc      = (const int*)d_in[13];     // [8000,5]
    float* out = (float*)d_out;                     // [50,128,283] fp32

    char* w = (char*)d_ws;                          // no overlays; ws >= ~40 MB
    u16*   WT_h    = (u16*)(w + 0);                 //    57,344
    u16*   WT_l    = (u16*)(w + 57344);             //    57,344
    u32*   whh_p   = (u32*)(w + 114688);            //    98,304
    float* w_ihT   = (float*)(w + 212992);          //   196,608
    u16*   emb_hiT = (u16*)(w + 409600);            // 2,048,000
    u16*   emb_loT = (u16*)(w + 2457600);           // 2,048,000
    float* emb_f   = (float*)(w + 4505600);         // 4,096,000
    float* partials= (float*)(w + 8601600);         // 16,384,000  [5][6400][128]
    float* GX      = (float*)(w + 24985600);        // 9,830,400   [6400][384]
    float* hidden  = (float*)(w + 34816000);        // 3,276,800   [6400][128]

    prep_watt_kernel<<<112, 256, 0, stream>>>(W_att, WT_h, WT_l);
    prep_whh_kernel<<<96, 256, 0, stream>>>(w_hh, whh_p);
    transpose_wih_kernel<<<192, 256, 0, stream>>>(w_ih, w_ihT);
    attn_mlp_kernel<<<320, 256, 0, stream>>>(W_emb, b_att, v_att, leaves, anc,
                                             WT_h, WT_l, emb_f);
    emb_split_kernel<<<125, 256, 0, stream>>>(emb_f, emb_hiT, emb_loT);
    gemm_xemb_kernel<<<1000, 256, 0, stream>>>(x, emb_hiT, emb_loT, partials);
    sumtanh_gx_kernel<<<400, 128, 0, stream>>>(partials, w_ihT, b_ih, GX);
    gru_scan_kernel<<<128, 384, 0, stream>>>(whh_p, b_hh, GX, hidden);
    logits_softmax_kernel<<<400, 128, 0, stream>>>(hidden, W_out, b_out, mask, out);
}

// Round 6
// 474.244 us; speedup vs baseline: 1.1594x; 1.1043x over previous
//
#include <hip/hip_runtime.h>

// GRAM model: ontology attention (MFMA) -> embedding projection (MFMA) -> GRU -> softmax
// Sizes: T=50 B=128 V=8000 NEMB=8728 E=128 H=128 ATT=100 C=283 L=5, M=T*B=6400
// dtypes: float tensors fp32 (inputs AND output); leaves/ancestors int32.

typedef unsigned short u16;
typedef unsigned int   u32;
typedef short bf16x8 __attribute__((ext_vector_type(8)));
typedef float f32x4  __attribute__((ext_vector_type(4)));

typedef __attribute__((address_space(1))) u32 gas_u32;
typedef __attribute__((address_space(3))) u32 las_u32;

union U4 { u32 u[4]; bf16x8 v; uint4 q; };

__device__ __forceinline__ float uaf(u32 u){ union{u32 u; float f;} c; c.u=u; return c.f; }
__device__ __forceinline__ u32 fau(float f){ union{u32 u; float f;} c; c.f=f; return c.u; }
__device__ __forceinline__ u16 f2bf(float f){ u32 u=fau(f); return (u16)((u + 0x7fffu + ((u>>16)&1u))>>16); }
__device__ __forceinline__ float sigm(float x){ return 1.f/(1.f+__expf(-x)); }

__device__ __forceinline__ void gll16(const void* g, void* l){
    __builtin_amdgcn_global_load_lds((const gas_u32*)g, (las_u32*)l, 16, 0, 0);
}

// split 8 consecutive floats into bf16-hi and bf16-lo packed fragments (RNE)
__device__ __forceinline__ void split8(const float* f, bf16x8* hi, bf16x8* lo){
    U4 H, L;
    #pragma unroll
    for (int j=0;j<4;++j){
        float f0=f[2*j], f1=f[2*j+1];
        u32 u0=fau(f0), u1=fau(f1);
        u32 t0=u0+0x7fffu+((u0>>16)&1u);
        u32 t1=u1+0x7fffu+((u1>>16)&1u);
        u32 h1=t1&0xffff0000u;
        H.u[j]=(t0>>16)|h1;
        float l0=f0-uaf(t0&0xffff0000u);
        float l1=f1-uaf(h1);
        u32 v0=fau(l0), v1=fau(l1);
        u32 s0=v0+0x7fffu+((v0>>16)&1u);
        u32 s1=v1+0x7fffu+((v1>>16)&1u);
        L.u[j]=(s0>>16)|(s1&0xffff0000u);
    }
    *hi=H.v; *lo=L.v;
}

__device__ __forceinline__ void split1(float f, u16& h, u16& l){
    u32 u=fau(f); u32 t=u+0x7fffu+((u>>16)&1u); h=(u16)(t>>16);
    float lf=f-uaf(t&0xffff0000u); l=f2bf(lf);
}

#define MFMA(a,b,c) __builtin_amdgcn_mfma_f32_16x16x32_bf16(a,b,c,0,0,0)

// ---------------------------------------------------------------------------
// prep: W_att [256][100] fp32 -> WT_h/WT_l [112][256] bf16 (rows >=100 zero)
__global__ __launch_bounds__(256,1) void prep_watt_kernel(
    const float* __restrict__ W_att, u16* __restrict__ WT_h, u16* __restrict__ WT_l)
{
    int n=blockIdx.x, k=threadIdx.x;          // n<112, k<256
    float f = (n<100)? W_att[k*100+n] : 0.f;
    u16 h,l; split1(f,h,l);
    WT_h[n*256+k]=h; WT_l[n*256+k]=l;
}

// prep: w_hh [384][128] fp32 -> bf16 pairs u32[384*64]
__global__ __launch_bounds__(256,1) void prep_whh_kernel(
    const float* __restrict__ whh, u32* __restrict__ out)
{
    int i=blockIdx.x*256+threadIdx.x;         // < 24576
    int j=i>>6, p=i&63;
    u32 a=(u32)f2bf(whh[j*128+2*p]);
    u32 b=(u32)f2bf(whh[j*128+2*p+1]);
    out[i]=a|(b<<16);
}

// prep: w_ihT[e][j] = w_ih[j][e] fp32
__global__ __launch_bounds__(256,1) void transpose_wih_kernel(
    const float* __restrict__ w_ih, float* __restrict__ w_ihT)
{
    int i=blockIdx.x*256+threadIdx.x;         // < 49152
    int e=i/384, j=i-e*384;
    w_ihT[i]=w_ih[j*128+e];
}

// ---------------------------------------------------------------------------
// Phase 1: attention MLP via MFMA + softmax over L + emb reduce (fp32).
// One block = 25 leaf codes = 125 (v,l) rows (pad to 128). N=112 (100 used), K=256.
// ---------------------------------------------------------------------------
__global__ __launch_bounds__(256,1) void attn_mlp_kernel(
    const float* __restrict__ W_emb, const float* __restrict__ b_att,
    const float* __restrict__ v_att, const int* __restrict__ leaves,
    const int* __restrict__ anc, const u16* __restrict__ WT_h,
    const u16* __restrict__ WT_l, float* __restrict__ emb_f)
{
    __shared__ __align__(16) char smem[61440];
    short* Ah=(short*)smem;                 // [128][64] bf16  16384 B
    short* Al=(short*)(smem+16384);         // 16384 B
    short* Bh=(short*)(smem+32768);         // [112][64] 14336 B
    short* Bl=(short*)(smem+47104);         // 14336 B
    float* mlp_s=(float*)smem;              // [128][112] fp32 (after MFMA, 57344 B)
    __shared__ float s_pre[128];
    __shared__ float s_vatt[112];
    __shared__ float s_attw[128];
    __shared__ int   s_leaf[128], s_anc[128];

    const int tid=threadIdx.x;
    const int wave=tid>>6, lane=tid&63;
    const int vb5=blockIdx.x*125;           // first (v,l) flat row

    if (tid<125){ s_leaf[tid]=leaves[vb5+tid]; s_anc[tid]=anc[vb5+tid]; }
    else if (tid<128){ s_leaf[tid]=leaves[vb5]; s_anc[tid]=anc[vb5]; }
    if (tid<100) s_vatt[tid]=v_att[tid];

    f32x4 acc[2][7];
    const f32x4 zf={0.f,0.f,0.f,0.f};
    #pragma unroll
    for (int mi=0;mi<2;++mi)
        #pragma unroll
        for (int ni=0;ni<7;++ni) acc[mi][ni]=zf;

    const int fr=lane&15, fq=lane>>4;

    for (int kc=0;kc<4;++kc){               // K chunks of 64: 0,1=leaf half, 2,3=anc half
        __syncthreads();
        {   // A: gather + hi/lo split; thread -> (row r=tid>>1, seg=tid&1: 32 floats)
            int r=tid>>1, seg=tid&1;
            int src=(kc<2)? s_leaf[r] : s_anc[r];
            const float* srcp = W_emb + (size_t)src*128 + (kc&1)*64 + seg*32;
            float buf[32];
            #pragma unroll
            for (int i=0;i<8;++i) *(f32x4*)(buf+4*i) = *(const f32x4*)(srcp+4*i);
            #pragma unroll
            for (int j=0;j<4;++j){
                bf16x8 hv, lv; split8(buf+8*j, &hv, &lv);
                U4 H,L; H.v=hv; L.v=lv;
                *(uint4*)&Ah[r*64+seg*32+j*8] = H.q;
                *(uint4*)&Al[r*64+seg*32+j*8] = L.q;
            }
        }
        // B: async global->LDS (rows are n, cols k-chunk)
        for (int c=wave;c<14;c+=4){
            size_t go=(size_t)(c*8+(lane>>3))*512 + (size_t)kc*128 + (size_t)(lane&7)*16;
            gll16((const char*)WT_h+go, Bh+c*512);
            gll16((const char*)WT_l+go, Bl+c*512);
        }
        __syncthreads();

        #pragma unroll
        for (int ks=0;ks<2;++ks){
            bf16x8 ah[2],al[2],bh[7],bl[7];
            #pragma unroll
            for (int mi=0;mi<2;++mi){
                int row=wave*32+mi*16+fr;
                ah[mi]=*(const bf16x8*)&Ah[row*64+ks*32+fq*8];
                al[mi]=*(const bf16x8*)&Al[row*64+ks*32+fq*8];
            }
            #pragma unroll
            for (int ni=0;ni<7;++ni){
                int rowb=ni*16+fr;
                bh[ni]=*(const bf16x8*)&Bh[rowb*64+ks*32+fq*8];
                bl[ni]=*(const bf16x8*)&Bl[rowb*64+ks*32+fq*8];
            }
            #pragma unroll
            for (int mi=0;mi<2;++mi)
                #pragma unroll
                for (int ni=0;ni<7;++ni){
                    acc[mi][ni]=MFMA(ah[mi],bh[ni],acc[mi][ni]);
                    acc[mi][ni]=MFMA(ah[mi],bl[ni],acc[mi][ni]);
                    acc[mi][ni]=MFMA(al[mi],bh[ni],acc[mi][ni]);
                }
        }
    }
    __syncthreads();
    // mlp = tanh(acc + b_att) -> LDS (C/D layout: col=lane&15, row=quad*4+reg)
    #pragma unroll
    for (int ni=0;ni<7;++ni){
        int col=ni*16+fr;
        float bb=(col<100)? b_att[col] : 0.f;
        #pragma unroll
        for (int mi=0;mi<2;++mi){
            int rb=wave*32+mi*16+fq*4;
            #pragma unroll
            for (int r=0;r<4;++r)
                mlp_s[(rb+r)*112+col]=tanhf(acc[mi][ni][r]+bb);
        }
    }
    __syncthreads();
    if (tid<128){
        float s=0.f;
        for (int n=0;n<100;++n) s+=mlp_s[tid*112+n]*s_vatt[n];
        s_pre[tid]=s;
    }
    __syncthreads();
    if (tid<25){    // softmax over L=5
        float p[5], mx=-1e30f;
        #pragma unroll
        for (int l=0;l<5;++l){ p[l]=s_pre[tid*5+l]; mx=fmaxf(mx,p[l]); }
        float s=0.f;
        #pragma unroll
        for (int l=0;l<5;++l){ p[l]=__expf(p[l]-mx); s+=p[l]; }
        float inv=1.f/s;
        #pragma unroll
        for (int l=0;l<5;++l) s_attw[tid*5+l]=p[l]*inv;
    }
    __syncthreads();
    for (int o=tid;o<3200;o+=256){   // emb[v][e] = sum_l att * an (fp32)
        int v=o>>7, e=o&127;
        float s=0.f;
        #pragma unroll
        for (int l=0;l<5;++l)
            s += s_attw[v*5+l]*W_emb[(size_t)s_anc[v*5+l]*128+e];
        emb_f[(size_t)(blockIdx.x*25+v)*128+e]=s;
    }
}

// ---------------------------------------------------------------------------
// Phase 1b: emb fp32 [8000][128] -> transposed bf16 hi/lo [128][8000]
__global__ __launch_bounds__(256,1) void emb_split_kernel(
    const float* __restrict__ emb_f, u16* __restrict__ hiT, u16* __restrict__ loT)
{
    __shared__ float tile[64*128];
    const int tid=threadIdx.x;
    const int vb=blockIdx.x*64;
    for (int i=tid;i<2048;i+=256){
        int row=i>>5, q=i&31;
        *(f32x4*)&tile[row*128+q*4] = *(const f32x4*)&emb_f[(size_t)(vb+row)*128+q*4];
    }
    __syncthreads();
    u32* hw=(u32*)hiT; u32* lw=(u32*)loT;
    for (int o=tid;o<4096;o+=256){
        int e=o>>5, p=o&31;
        float f0=tile[(2*p)*128+e], f1=tile[(2*p+1)*128+e];
        u16 h0,l0,h1,l1; split1(f0,h0,l0); split1(f1,h1,l1);
        size_t base=(size_t)e*4000 + (size_t)(vb>>1) + p;
        hw[base]=(u32)h0|((u32)h1<<16);
        lw[base]=(u32)l0|((u32)l1<<16);
    }
}

// ---------------------------------------------------------------------------
// Phase 2: partials[ks][m][e] = x[m, k-slice] @ emb[k-slice, e]
// M-tile 32, N=128, splitK=5 -> 1000 blocks, 40 KB LDS -> 4 blocks/CU.
// A: VGPR staging (dwordx4 x2) -> split8 ONCE -> ds_write_b128 bf16 hi/lo,
//    swizzled chunk c->c^(r&7); next iter's A floats register-prefetched.
// B: gll16 with swizzle in the per-lane global address (0 conflicts, r5).
// 3-combo MFMA (hh + hl + lh).
// ---------------------------------------------------------------------------
__global__ __launch_bounds__(256,4) void gemm_xemb_kernel(
    const float* __restrict__ x, const u16* __restrict__ bhT, const u16* __restrict__ blT,
    float* __restrict__ partials)
{
    __shared__ __align__(16) short Ah[32*64];     // 4 KB  (chunk c of row r at c^(r&7))
    __shared__ __align__(16) short Al[32*64];     // 4 KB
    __shared__ __align__(16) short Bh[128*64];    // 16 KB (chunk c of row r at c^(r&7))
    __shared__ __align__(16) short Bl[128*64];    // 16 KB

    const int tid=threadIdx.x, wave=tid>>6, lane=tid&63;
    const int mt=blockIdx.x%200, ks=blockIdx.x/200;
    const int mbase=mt*32;
    const int k0=ks*1600;

    f32x4 acc[2][2];
    const f32x4 zf={0.f,0.f,0.f,0.f};
    #pragma unroll
    for (int i=0;i<2;++i)
        #pragma unroll
        for (int j=0;j<2;++j) acc[i][j]=zf;

    const char* bhb=(const char*)bhT;
    const char* blb=(const char*)blT;
    const int fr=lane&15, fq=lane>>4;
    const int nbase=wave*32;

    // A staging: thread -> row sr (0..31), logical chunk sc (8 floats)
    const int sr=tid>>3, sc=tid&7;
    const float* agp = x + (size_t)(mbase+sr)*8000 + k0 + sc*8;
    bf16x8* awh = (bf16x8*)&Ah[sr*64 + ((sc^(sr&7))<<3)];
    bf16x8* awl = (bf16x8*)&Al[sr*64 + ((sc^(sr&7))<<3)];

    // B staging coords (per-lane row/chunk inside each 8-row group)
    const int br=lane>>3, bc0=lane&7;

    f32x4 pa0 = *(const f32x4*)agp;
    f32x4 pa1 = *(const f32x4*)(agp+4);

    for (int kk=k0; kk<k0+1600; kk+=64){
        __syncthreads();
        {   // convert once, write bf16 hi/lo tiles
            float buf[8];
            *(f32x4*)&buf[0]=pa0; *(f32x4*)&buf[4]=pa1;
            bf16x8 hv,lv; split8(buf,&hv,&lv);
            *awh=hv; *awl=lv;
        }
        #pragma unroll
        for (int ii=0;ii<4;++ii){
            int s=wave*4+ii;
            int r=s*8+br;
            int c=bc0^(r&7);
            size_t go=((size_t)r*8000 + kk + c*8)*2;
            gll16(bhb+go, (char*)Bh + (size_t)s*1024);
            gll16(blb+go, (char*)Bl + (size_t)s*1024);
        }
        __syncthreads();

        // register-prefetch next iter's A floats (hidden under compute)
        if (kk+64 < k0+1600){
            const float* ag = agp + (kk + 64 - k0);
            pa0=*(const f32x4*)ag; pa1=*(const f32x4*)(ag+4);
        }

        #pragma unroll
        for (int kh=0;kh<2;++kh){
            bf16x8 ah[2],al[2],bh[2],bl[2];
            #pragma unroll
            for (int mi=0;mi<2;++mi){
                int row=mi*16+fr;
                int ci=(kh*4+fq)^(row&7);
                ah[mi]=*(const bf16x8*)&Ah[row*64+ci*8];
                al[mi]=*(const bf16x8*)&Al[row*64+ci*8];
            }
            #pragma unroll
            for (int ni=0;ni<2;++ni){
                int rowb=nbase+ni*16+fr;
                int ch=rowb*8+((kh*4+fq)^(rowb&7));
                bh[ni]=*(const bf16x8*)&Bh[ch*8];
                bl[ni]=*(const bf16x8*)&Bl[ch*8];
            }
            #pragma unroll
            for (int mi=0;mi<2;++mi)
                #pragma unroll
                for (int ni=0;ni<2;++ni){
                    acc[mi][ni]=MFMA(ah[mi],bh[ni],acc[mi][ni]);
                    acc[mi][ni]=MFMA(ah[mi],bl[ni],acc[mi][ni]);
                    acc[mi][ni]=MFMA(al[mi],bh[ni],acc[mi][ni]);
                }
        }
    }

    float* pout=partials + ((size_t)ks*6400+mbase)*128;
    #pragma unroll
    for (int mi=0;mi<2;++mi)
        #pragma unroll
        for (int ni=0;ni<2;++ni)
            #pragma unroll
            for (int r=0;r<4;++r)
                pout[(size_t)(mi*16+fq*4+r)*128 + nbase+ni*16+fr]=acc[mi][ni][r];
}

// ---------------------------------------------------------------------------
// Phase 2b+3a fused: x_emb = tanh(sum partials); GX = x_emb @ w_ih^T + b_ih
// 384 threads (6 waves), one output column per thread, 16 rows per block.
__global__ __launch_bounds__(384,2) void sumtanh_gx_kernel(
    const float* __restrict__ partials, const float* __restrict__ w_ihT,
    const float* __restrict__ b_ih, float* __restrict__ GX)
{
    __shared__ float sx[2048];
    const int tid=threadIdx.x;
    const int rb=blockIdx.x*16;
    for (int i=tid;i<2048;i+=384){
        size_t o=(size_t)rb*128+i;
        float s=0.f;
        #pragma unroll
        for (int k=0;k<5;++k) s+=partials[(size_t)k*819200+o];
        sx[i]=tanhf(s);
    }
    __syncthreads();

    float acc[16];
    #pragma unroll
    for (int r=0;r<16;++r) acc[r]=0.f;
    for (int e=0;e<128;++e){
        float w0=w_ihT[e*384+tid];
        #pragma unroll
        for (int r=0;r<16;++r) acc[r]=fmaf(sx[r*128+e],w0,acc[r]);
    }
    float b0=b_ih[tid];
    #pragma unroll
    for (int r=0;r<16;++r)
        GX[(size_t)(rb+r)*384+tid]=acc[r]+b0;
}

// ---------------------------------------------------------------------------
// Phase 3b: GRU scan, one block per batch element.
// w_hh pre-unpacked to 128 fp32 VGPRs; h stored bf16 in LDS; h_prev in register;
// GX for step t+1 register-prefetched during step t's matvec.
// ---------------------------------------------------------------------------
__global__ __launch_bounds__(384,1) void gru_scan_kernel(
    const u32* __restrict__ whh_p, const float* __restrict__ b_hh,
    const float* __restrict__ GX, float* __restrict__ hidden)
{
    __shared__ __align__(16) u16 shb[128];   // h as bf16
    __shared__ float sgh[384];
    const int tid=threadIdx.x, b=blockIdx.x;

    float wf[128];
    #pragma unroll
    for (int q=0;q<64;++q){
        u32 u=whh_p[tid*64+q];
        wf[2*q]  =uaf(u<<16);
        wf[2*q+1]=uaf(u&0xffff0000u);
    }
    float hreg=0.f;
    if (tid<128) shb[tid]=0;
    const float bb=b_hh[tid];

    float gx0=0.f,gx1=0.f,gx2=0.f;
    if (tid<128){
        const float* gp=GX+(size_t)b*384;
        gx0=gp[tid]; gx1=gp[128+tid]; gx2=gp[256+tid];
    }
    __syncthreads();

    for (int t=0;t<50;++t){
        float nx0=0.f,nx1=0.f,nx2=0.f;
        if (tid<128 && t<49){
            const float* gp=GX+((size_t)(t+1)*128+b)*384;
            nx0=gp[tid]; nx1=gp[128+tid]; nx2=gp[256+tid];
        }
        float acc=0.f;
        #pragma unroll
        for (int p=0;p<16;++p){
            U4 c; c.v=*(const bf16x8*)&shb[p*8];
            #pragma unroll
            for (int j=0;j<4;++j){
                u32 u=c.u[j];
                acc=fmaf(uaf(u<<16),         wf[p*8+2*j],   acc);
                acc=fmaf(uaf(u&0xffff0000u), wf[p*8+2*j+1], acc);
            }
        }
        sgh[tid]=acc+bb;
        __syncthreads();
        if (tid<128){
            float r=sigm(gx0+sgh[tid]);
            float z=sigm(gx1+sgh[128+tid]);
            float n=tanhf(gx2+r*sgh[256+tid]);
            float hn=(1.f-z)*n+z*hreg;
            hreg=hn;
            hidden[((size_t)t*128+b)*128+tid]=hn;
            shb[tid]=f2bf(hn);
        }
        __syncthreads();
        gx0=nx0; gx1=nx1; gx2=nx2;
    }
}

// ---------------------------------------------------------------------------
// Phase 4 fused: logits -> row softmax -> * mask -> out. 16 rows/block,
// 320 threads (5 waves), one class column per thread (283 active).
__global__ __launch_bounds__(320,2) void logits_softmax_kernel(
    const float* __restrict__ hidden, const float* __restrict__ W_out,
    const float* __restrict__ b_out, const float* __restrict__ mask,
    float* __restrict__ out)
{
    __shared__ float shd[2048];
    __shared__ float slog[16*288];
    const int tid=threadIdx.x;
    const int rb=blockIdx.x*16;
    for (int i=tid;i<2048;i+=320) shd[i]=hidden[(size_t)rb*128+i];
    __syncthreads();

    const bool act=(tid<283);
    const int cl=act? tid : 282;
    float acc[16];
    #pragma unroll
    for (int r=0;r<16;++r) acc[r]=0.f;
    for (int h=0;h<128;++h){
        float w0=W_out[h*283+cl];
        #pragma unroll
        for (int r=0;r<16;++r) acc[r]=fmaf(shd[r*128+h],w0,acc[r]);
    }
    float b0=b_out[cl];
    if (act){
        #pragma unroll
        for (int r=0;r<16;++r) slog[r*288+tid]=acc[r]+b0;
    }
    __syncthreads();

    // softmax: waves 0..3 handle 4 rows each
    const int wv=tid>>6, lane=tid&63;
    if (wv<4){
        #pragma unroll
        for (int rr=0;rr<4;++rr){
            int r=wv*4+rr;
            int m=rb+r;
            float v[5];
            float mx=-1e30f;
            #pragma unroll
            for (int i=0;i<5;++i){
                int c=lane+i*64;
                v[i]=(c<283)? slog[r*288+c] : -1e30f;
                mx=fmaxf(mx,v[i]);
            }
            #pragma unroll
            for (int off=32;off>0;off>>=1) mx=fmaxf(mx,__shfl_xor(mx,off,64));
            float s=0.f;
            #pragma unroll
            for (int i=0;i<5;++i){
                int c=lane+i*64;
                v[i]=(c<283)? __expf(v[i]-mx) : 0.f;
                s+=v[i];
            }
            #pragma unroll
            for (int off=32;off>0;off>>=1) s+=__shfl_xor(s,off,64);
            const float sc=mask[m]/s;
            float* op=out+(size_t)m*283;
            #pragma unroll
            for (int i=0;i<5;++i){
                int c=lane+i*64;
                if (c<283) op[c]=v[i]*sc;
            }
        }
    }
}

// ---------------------------------------------------------------------------
extern "C" void kernel_launch(void* const* d_in, const int* in_sizes, int n_in,
                              void* d_out, int out_size, void* d_ws, size_t ws_size,
                              hipStream_t stream) {
    const float* x      = (const float*)d_in[0];    // [50,128,8000]
    const float* mask   = (const float*)d_in[1];    // [50,128]
    const float* W_emb  = (const float*)d_in[2];    // [8728,128]
    const float* W_att  = (const float*)d_in[3];    // [256,100]
    const float* b_att  = (const float*)d_in[4];    // [100]
    const float* v_att  = (const float*)d_in[5];    // [100]
    const float* w_ih   = (const float*)d_in[6];    // [384,128]
    const float* w_hh   = (const float*)d_in[7];    // [384,128]
    const float* b_ih   = (const float*)d_in[8];    // [384]
    const float* b_hh   = (const float*)d_in[9];    // [384]
    const float* W_out  = (const float*)d_in[10];   // [128,283]
    const float* b_out  = (const float*)d_in[11];   // [283]
    const int* leaves   = (const int*)d_in[12];     // [8000,5]
    const int* anc      = (const int*)d_in[13];     // [8000,5]
    float* out = (float*)d_out;                     // [50,128,283] fp32

    char* w = (char*)d_ws;                          // no overlays
    u16*   WT_h    = (u16*)(w + 0);                 //    57,344
    u16*   WT_l    = (u16*)(w + 57344);             //    57,344
    u32*   whh_p   = (u32*)(w + 114688);            //    98,304
    float* w_ihT   = (float*)(w + 212992);          //   196,608
    u16*   emb_hiT = (u16*)(w + 409600);            // 2,048,000
    u16*   emb_loT = (u16*)(w + 2457600);           // 2,048,000
    float* emb_f   = (float*)(w + 4505600);         // 4,096,000
    float* partials= (float*)(w + 8601600);         // 16,384,000  [5][6400][128]
    float* GX      = (float*)(w + 24985600);        // 9,830,400   [6400][384]
    float* hidden  = (float*)(w + 34816000);        // 3,276,800   [6400][128]

    prep_watt_kernel<<<112, 256, 0, stream>>>(W_att, WT_h, WT_l);
    prep_whh_kernel<<<96, 256, 0, stream>>>(w_hh, whh_p);
    transpose_wih_kernel<<<192, 256, 0, stream>>>(w_ih, w_ihT);
    attn_mlp_kernel<<<320, 256, 0, stream>>>(W_emb, b_att, v_att, leaves, anc,
                                             WT_h, WT_l, emb_f);
    emb_split_kernel<<<125, 256, 0, stream>>>(emb_f, emb_hiT, emb_loT);
    gemm_xemb_kernel<<<1000, 256, 0, stream>>>(x, emb_hiT, emb_loT, partials);
    sumtanh_gx_kernel<<<400, 384, 0, stream>>>(partials, w_ihT, b_ih, GX);
    gru_scan_kernel<<<128, 384, 0, stream>>>(whh_p, b_hh, GX, hidden);
    logits_softmax_kernel<<<400, 320, 0, stream>>>(hidden, W_out, b_out, mask, out);
}

// Round 7
// 462.386 us; speedup vs baseline: 1.1891x; 1.0256x over previous
//
#include <hip/hip_runtime.h>

// GRAM model: ontology attention (MFMA) -> embedding projection (MFMA) -> GRU -> softmax
// Sizes: T=50 B=128 V=8000 NEMB=8728 E=128 H=128 ATT=100 C=283 L=5, M=T*B=6400
// dtypes: float tensors fp32 (inputs AND output); leaves/ancestors int32.

typedef unsigned short u16;
typedef unsigned int   u32;
typedef short bf16x8 __attribute__((ext_vector_type(8)));
typedef float f32x4  __attribute__((ext_vector_type(4)));

typedef __attribute__((address_space(1))) u32 gas_u32;
typedef __attribute__((address_space(3))) u32 las_u32;

union U4 { u32 u[4]; bf16x8 v; uint4 q; };

__device__ __forceinline__ float uaf(u32 u){ union{u32 u; float f;} c; c.u=u; return c.f; }
__device__ __forceinline__ u32 fau(float f){ union{u32 u; float f;} c; c.f=f; return c.u; }
__device__ __forceinline__ u16 f2bf(float f){ u32 u=fau(f); return (u16)((u + 0x7fffu + ((u>>16)&1u))>>16); }
__device__ __forceinline__ float sigm(float x){ return 1.f/(1.f+__expf(-x)); }

__device__ __forceinline__ void gll16(const void* g, void* l){
    __builtin_amdgcn_global_load_lds((const gas_u32*)g, (las_u32*)l, 16, 0, 0);
}

// split 8 consecutive floats into bf16-hi and bf16-lo packed fragments (RNE)
__device__ __forceinline__ void split8(const float* f, bf16x8* hi, bf16x8* lo){
    U4 H, L;
    #pragma unroll
    for (int j=0;j<4;++j){
        float f0=f[2*j], f1=f[2*j+1];
        u32 u0=fau(f0), u1=fau(f1);
        u32 t0=u0+0x7fffu+((u0>>16)&1u);
        u32 t1=u1+0x7fffu+((u1>>16)&1u);
        u32 h1=t1&0xffff0000u;
        H.u[j]=(t0>>16)|h1;
        float l0=f0-uaf(t0&0xffff0000u);
        float l1=f1-uaf(h1);
        u32 v0=fau(l0), v1=fau(l1);
        u32 s0=v0+0x7fffu+((v0>>16)&1u);
        u32 s1=v1+0x7fffu+((v1>>16)&1u);
        L.u[j]=(s0>>16)|(s1&0xffff0000u);
    }
    *hi=H.v; *lo=L.v;
}

__device__ __forceinline__ void split1(float f, u16& h, u16& l){
    u32 u=fau(f); u32 t=u+0x7fffu+((u>>16)&1u); h=(u16)(t>>16);
    float lf=f-uaf(t&0xffff0000u); l=f2bf(lf);
}

#define MFMA(a,b,c) __builtin_amdgcn_mfma_f32_16x16x32_bf16(a,b,c,0,0,0)

// ---------------------------------------------------------------------------
// merged prep (one launch):
//  blocks [0,112):   W_att [256][100] -> WT_h/WT_l [112][256] bf16 (rows>=100 zero)
//  blocks [112,208): w_hh [384][128] -> bf16 pairs u32[384*64]
//  blocks [208,400): w_ihT[e][j] = w_ih[j][e] fp32
__global__ __launch_bounds__(256,1) void prep_kernel(
    const float* __restrict__ W_att, u16* __restrict__ WT_h, u16* __restrict__ WT_l,
    const float* __restrict__ whh, u32* __restrict__ whh_p,
    const float* __restrict__ w_ih, float* __restrict__ w_ihT)
{
    const int bid=blockIdx.x, tid=threadIdx.x;
    if (bid<112){
        int n=bid, k=tid;
        float f=(n<100)? W_att[k*100+n] : 0.f;
        u16 h,l; split1(f,h,l);
        WT_h[n*256+k]=h; WT_l[n*256+k]=l;
    } else if (bid<208){
        int i=(bid-112)*256+tid;              // < 24576
        int j=i>>6, p=i&63;
        u32 a=(u32)f2bf(whh[j*128+2*p]);
        u32 b=(u32)f2bf(whh[j*128+2*p+1]);
        whh_p[i]=a|(b<<16);
    } else {
        int i=(bid-208)*256+tid;              // < 49152
        int e=i/384, j=i-e*384;
        w_ihT[i]=w_ih[j*128+e];
    }
}

// ---------------------------------------------------------------------------
// Phase 1: attention MLP via MFMA + softmax over L + emb reduce (fp32).
// One block = 25 leaf codes = 125 (v,l) rows (pad to 128). N=112 (100 used), K=256.
// ---------------------------------------------------------------------------
__global__ __launch_bounds__(256,1) void attn_mlp_kernel(
    const float* __restrict__ W_emb, const float* __restrict__ b_att,
    const float* __restrict__ v_att, const int* __restrict__ leaves,
    const int* __restrict__ anc, const u16* __restrict__ WT_h,
    const u16* __restrict__ WT_l, float* __restrict__ emb_f)
{
    __shared__ __align__(16) char smem[61440];
    short* Ah=(short*)smem;                 // [128][64] bf16  16384 B
    short* Al=(short*)(smem+16384);         // 16384 B
    short* Bh=(short*)(smem+32768);         // [112][64] 14336 B
    short* Bl=(short*)(smem+47104);         // 14336 B
    float* mlp_s=(float*)smem;              // [128][112] fp32 (after MFMA, 57344 B)
    __shared__ float s_pre[128];
    __shared__ float s_vatt[112];
    __shared__ float s_attw[128];
    __shared__ int   s_leaf[128], s_anc[128];

    const int tid=threadIdx.x;
    const int wave=tid>>6, lane=tid&63;
    const int vb5=blockIdx.x*125;           // first (v,l) flat row

    if (tid<125){ s_leaf[tid]=leaves[vb5+tid]; s_anc[tid]=anc[vb5+tid]; }
    else if (tid<128){ s_leaf[tid]=leaves[vb5]; s_anc[tid]=anc[vb5]; }
    if (tid<100) s_vatt[tid]=v_att[tid];

    f32x4 acc[2][7];
    const f32x4 zf={0.f,0.f,0.f,0.f};
    #pragma unroll
    for (int mi=0;mi<2;++mi)
        #pragma unroll
        for (int ni=0;ni<7;++ni) acc[mi][ni]=zf;

    const int fr=lane&15, fq=lane>>4;

    for (int kc=0;kc<4;++kc){               // K chunks of 64: 0,1=leaf half, 2,3=anc half
        __syncthreads();
        {   // A: gather + hi/lo split; thread -> (row r=tid>>1, seg=tid&1: 32 floats)
            int r=tid>>1, seg=tid&1;
            int src=(kc<2)? s_leaf[r] : s_anc[r];
            const float* srcp = W_emb + (size_t)src*128 + (kc&1)*64 + seg*32;
            float buf[32];
            #pragma unroll
            for (int i=0;i<8;++i) *(f32x4*)(buf+4*i) = *(const f32x4*)(srcp+4*i);
            #pragma unroll
            for (int j=0;j<4;++j){
                bf16x8 hv, lv; split8(buf+8*j, &hv, &lv);
                U4 H,L; H.v=hv; L.v=lv;
                *(uint4*)&Ah[r*64+seg*32+j*8] = H.q;
                *(uint4*)&Al[r*64+seg*32+j*8] = L.q;
            }
        }
        // B: async global->LDS (rows are n, cols k-chunk)
        for (int c=wave;c<14;c+=4){
            size_t go=(size_t)(c*8+(lane>>3))*512 + (size_t)kc*128 + (size_t)(lane&7)*16;
            gll16((const char*)WT_h+go, Bh+c*512);
            gll16((const char*)WT_l+go, Bl+c*512);
        }
        __syncthreads();

        #pragma unroll
        for (int ks=0;ks<2;++ks){
            bf16x8 ah[2],al[2],bh[7],bl[7];
            #pragma unroll
            for (int mi=0;mi<2;++mi){
                int row=wave*32+mi*16+fr;
                ah[mi]=*(const bf16x8*)&Ah[row*64+ks*32+fq*8];
                al[mi]=*(const bf16x8*)&Al[row*64+ks*32+fq*8];
            }
            #pragma unroll
            for (int ni=0;ni<7;++ni){
                int rowb=ni*16+fr;
                bh[ni]=*(const bf16x8*)&Bh[rowb*64+ks*32+fq*8];
                bl[ni]=*(const bf16x8*)&Bl[rowb*64+ks*32+fq*8];
            }
            #pragma unroll
            for (int mi=0;mi<2;++mi)
                #pragma unroll
                for (int ni=0;ni<7;++ni){
                    acc[mi][ni]=MFMA(ah[mi],bh[ni],acc[mi][ni]);
                    acc[mi][ni]=MFMA(ah[mi],bl[ni],acc[mi][ni]);
                    acc[mi][ni]=MFMA(al[mi],bh[ni],acc[mi][ni]);
                }
        }
    }
    __syncthreads();
    // mlp = tanh(acc + b_att) -> LDS (C/D layout: col=lane&15, row=quad*4+reg)
    #pragma unroll
    for (int ni=0;ni<7;++ni){
        int col=ni*16+fr;
        float bb=(col<100)? b_att[col] : 0.f;
        #pragma unroll
        for (int mi=0;mi<2;++mi){
            int rb=wave*32+mi*16+fq*4;
            #pragma unroll
            for (int r=0;r<4;++r)
                mlp_s[(rb+r)*112+col]=tanhf(acc[mi][ni][r]+bb);
        }
    }
    __syncthreads();
    if (tid<128){
        float s=0.f;
        for (int n=0;n<100;++n) s+=mlp_s[tid*112+n]*s_vatt[n];
        s_pre[tid]=s;
    }
    __syncthreads();
    if (tid<25){    // softmax over L=5
        float p[5], mx=-1e30f;
        #pragma unroll
        for (int l=0;l<5;++l){ p[l]=s_pre[tid*5+l]; mx=fmaxf(mx,p[l]); }
        float s=0.f;
        #pragma unroll
        for (int l=0;l<5;++l){ p[l]=__expf(p[l]-mx); s+=p[l]; }
        float inv=1.f/s;
        #pragma unroll
        for (int l=0;l<5;++l) s_attw[tid*5+l]=p[l]*inv;
    }
    __syncthreads();
    for (int o=tid;o<3200;o+=256){   // emb[v][e] = sum_l att * an (fp32)
        int v=o>>7, e=o&127;
        float s=0.f;
        #pragma unroll
        for (int l=0;l<5;++l)
            s += s_attw[v*5+l]*W_emb[(size_t)s_anc[v*5+l]*128+e];
        emb_f[(size_t)(blockIdx.x*25+v)*128+e]=s;
    }
}

// ---------------------------------------------------------------------------
// Phase 1b: emb fp32 [8000][128] -> transposed bf16 hi/lo [128][8000]
__global__ __launch_bounds__(256,1) void emb_split_kernel(
    const float* __restrict__ emb_f, u16* __restrict__ hiT, u16* __restrict__ loT)
{
    __shared__ float tile[64*128];
    const int tid=threadIdx.x;
    const int vb=blockIdx.x*64;
    for (int i=tid;i<2048;i+=256){
        int row=i>>5, q=i&31;
        *(f32x4*)&tile[row*128+q*4] = *(const f32x4*)&emb_f[(size_t)(vb+row)*128+q*4];
    }
    __syncthreads();
    u32* hw=(u32*)hiT; u32* lw=(u32*)loT;
    for (int o=tid;o<4096;o+=256){
        int e=o>>5, p=o&31;
        float f0=tile[(2*p)*128+e], f1=tile[(2*p+1)*128+e];
        u16 h0,l0,h1,l1; split1(f0,h0,l0); split1(f1,h1,l1);
        size_t base=(size_t)e*4000 + (size_t)(vb>>1) + p;
        hw[base]=(u32)h0|((u32)h1<<16);
        lw[base]=(u32)l0|((u32)l1<<16);
    }
}

// ---------------------------------------------------------------------------
// Phase 2: partials[ks][m][e] = x[m, k-slice] @ emb[k-slice, e]
// M-tile 64, N=128, splitK=5 -> 500 blocks, 48 KB LDS -> 3 blocks/CU.
// Per K-iter per wave: 48 MFMAs / 24 fragment reads (2.0 ratio) — longer
// compute phase per barrier to cover the B-load drain.
// A: VGPR staging -> split8 once -> ds_write_b128, swizzle c^(r&7);
//    next iter's A floats register-prefetched (4x f32x4).
// B: gll16, swizzle in the per-lane global address (0 conflicts, r5/r6).
// ---------------------------------------------------------------------------
__global__ __launch_bounds__(256,3) void gemm_xemb_kernel(
    const float* __restrict__ x, const u16* __restrict__ bhT, const u16* __restrict__ blT,
    float* __restrict__ partials)
{
    __shared__ __align__(16) short Ah[64*64];     // 8 KB  (chunk c of row r at c^(r&7))
    __shared__ __align__(16) short Al[64*64];     // 8 KB
    __shared__ __align__(16) short Bh[128*64];    // 16 KB
    __shared__ __align__(16) short Bl[128*64];    // 16 KB

    const int tid=threadIdx.x, wave=tid>>6, lane=tid&63;
    const int mt=blockIdx.x%100, ks=blockIdx.x/100;
    const int mbase=mt*64;
    const int k0=ks*1600;

    f32x4 acc[4][2];
    const f32x4 zf={0.f,0.f,0.f,0.f};
    #pragma unroll
    for (int i=0;i<4;++i)
        #pragma unroll
        for (int j=0;j<2;++j) acc[i][j]=zf;

    const char* bhb=(const char*)bhT;
    const char* blb=(const char*)blT;
    const int fr=lane&15, fq=lane>>4;
    const int nbase=wave*32;

    // A staging: thread -> row sr (0..63), logical chunks sc, sc+1 (8 floats each)
    const int sr=tid>>2, sc=(tid&3)*2;
    const float* agp = x + (size_t)(mbase+sr)*8000 + k0 + sc*8;
    bf16x8* awh0=(bf16x8*)&Ah[sr*64 + (((sc  )^(sr&7))<<3)];
    bf16x8* awl0=(bf16x8*)&Al[sr*64 + (((sc  )^(sr&7))<<3)];
    bf16x8* awh1=(bf16x8*)&Ah[sr*64 + (((sc+1)^(sr&7))<<3)];
    bf16x8* awl1=(bf16x8*)&Al[sr*64 + (((sc+1)^(sr&7))<<3)];

    // B staging coords (per-lane row/chunk inside each 8-row group)
    const int br=lane>>3, bc0=lane&7;

    f32x4 pa0=*(const f32x4*)agp,     pa1=*(const f32x4*)(agp+4);
    f32x4 pa2=*(const f32x4*)(agp+8), pa3=*(const f32x4*)(agp+12);

    for (int kk=k0; kk<k0+1600; kk+=64){
        __syncthreads();
        {   // convert once, write bf16 hi/lo tiles
            float buf[8];
            bf16x8 hv,lv;
            *(f32x4*)&buf[0]=pa0; *(f32x4*)&buf[4]=pa1;
            split8(buf,&hv,&lv); *awh0=hv; *awl0=lv;
            *(f32x4*)&buf[0]=pa2; *(f32x4*)&buf[4]=pa3;
            split8(buf,&hv,&lv); *awh1=hv; *awl1=lv;
        }
        #pragma unroll
        for (int ii=0;ii<4;++ii){
            int s=wave*4+ii;
            int r=s*8+br;
            int c=bc0^(r&7);
            size_t go=((size_t)r*8000 + kk + c*8)*2;
            gll16(bhb+go, (char*)Bh + (size_t)s*1024);
            gll16(blb+go, (char*)Bl + (size_t)s*1024);
        }
        __syncthreads();

        // register-prefetch next iter's A floats (hidden under compute)
        if (kk+64 < k0+1600){
            const float* ag = agp + (kk+64-k0);
            pa0=*(const f32x4*)ag;     pa1=*(const f32x4*)(ag+4);
            pa2=*(const f32x4*)(ag+8); pa3=*(const f32x4*)(ag+12);
        }

        #pragma unroll
        for (int kh=0;kh<2;++kh){
            bf16x8 ah[4],al[4],bh[2],bl[2];
            #pragma unroll
            for (int mi=0;mi<4;++mi){
                int row=mi*16+fr;
                int ci=(kh*4+fq)^(row&7);
                ah[mi]=*(const bf16x8*)&Ah[row*64+ci*8];
                al[mi]=*(const bf16x8*)&Al[row*64+ci*8];
            }
            #pragma unroll
            for (int ni=0;ni<2;++ni){
                int rowb=nbase+ni*16+fr;
                int ch=rowb*8+((kh*4+fq)^(rowb&7));
                bh[ni]=*(const bf16x8*)&Bh[ch*8];
                bl[ni]=*(const bf16x8*)&Bl[ch*8];
            }
            #pragma unroll
            for (int mi=0;mi<4;++mi)
                #pragma unroll
                for (int ni=0;ni<2;++ni){
                    acc[mi][ni]=MFMA(ah[mi],bh[ni],acc[mi][ni]);
                    acc[mi][ni]=MFMA(ah[mi],bl[ni],acc[mi][ni]);
                    acc[mi][ni]=MFMA(al[mi],bh[ni],acc[mi][ni]);
                }
        }
    }

    float* pout=partials + ((size_t)ks*6400+mbase)*128;
    #pragma unroll
    for (int mi=0;mi<4;++mi)
        #pragma unroll
        for (int ni=0;ni<2;++ni)
            #pragma unroll
            for (int r=0;r<4;++r)
                pout[(size_t)(mi*16+fq*4+r)*128 + nbase+ni*16+fr]=acc[mi][ni][r];
}

// ---------------------------------------------------------------------------
// Phase 2b+3a fused: x_emb = tanh(sum partials); GX = x_emb @ w_ih^T + b_ih
// 384 threads (6 waves), one output column per thread, 16 rows per block.
__global__ __launch_bounds__(384,2) void sumtanh_gx_kernel(
    const float* __restrict__ partials, const float* __restrict__ w_ihT,
    const float* __restrict__ b_ih, float* __restrict__ GX)
{
    __shared__ float sx[2048];
    const int tid=threadIdx.x;
    const int rb=blockIdx.x*16;
    for (int i=tid;i<2048;i+=384){
        size_t o=(size_t)rb*128+i;
        float s=0.f;
        #pragma unroll
        for (int k=0;k<5;++k) s+=partials[(size_t)k*819200+o];
        sx[i]=tanhf(s);
    }
    __syncthreads();

    float acc[16];
    #pragma unroll
    for (int r=0;r<16;++r) acc[r]=0.f;
    for (int e=0;e<128;++e){
        float w0=w_ihT[e*384+tid];
        #pragma unroll
        for (int r=0;r<16;++r) acc[r]=fmaf(sx[r*128+e],w0,acc[r]);
    }
    float b0=b_ih[tid];
    #pragma unroll
    for (int r=0;r<16;++r)
        GX[(size_t)(rb+r)*384+tid]=acc[r]+b0;
}

// ---------------------------------------------------------------------------
// Phase 3b: GRU scan, one block per batch element.
// w_hh pre-unpacked to 128 fp32 VGPRs; h stored bf16 in LDS; h_prev in register;
// GX for step t+1 register-prefetched during step t's matvec.
// ---------------------------------------------------------------------------
__global__ __launch_bounds__(384,1) void gru_scan_kernel(
    const u32* __restrict__ whh_p, const float* __restrict__ b_hh,
    const float* __restrict__ GX, float* __restrict__ hidden)
{
    __shared__ __align__(16) u16 shb[128];   // h as bf16
    __shared__ float sgh[384];
    const int tid=threadIdx.x, b=blockIdx.x;

    float wf[128];
    #pragma unroll
    for (int q=0;q<64;++q){
        u32 u=whh_p[tid*64+q];
        wf[2*q]  =uaf(u<<16);
        wf[2*q+1]=uaf(u&0xffff0000u);
    }
    float hreg=0.f;
    if (tid<128) shb[tid]=0;
    const float bb=b_hh[tid];

    float gx0=0.f,gx1=0.f,gx2=0.f;
    if (tid<128){
        const float* gp=GX+(size_t)b*384;
        gx0=gp[tid]; gx1=gp[128+tid]; gx2=gp[256+tid];
    }
    __syncthreads();

    for (int t=0;t<50;++t){
        float nx0=0.f,nx1=0.f,nx2=0.f;
        if (tid<128 && t<49){
            const float* gp=GX+((size_t)(t+1)*128+b)*384;
            nx0=gp[tid]; nx1=gp[128+tid]; nx2=gp[256+tid];
        }
        float acc=0.f;
        #pragma unroll
        for (int p=0;p<16;++p){
            U4 c; c.v=*(const bf16x8*)&shb[p*8];
            #pragma unroll
            for (int j=0;j<4;++j){
                u32 u=c.u[j];
                acc=fmaf(uaf(u<<16),         wf[p*8+2*j],   acc);
                acc=fmaf(uaf(u&0xffff0000u), wf[p*8+2*j+1], acc);
            }
        }
        sgh[tid]=acc+bb;
        __syncthreads();
        if (tid<128){
            float r=sigm(gx0+sgh[tid]);
            float z=sigm(gx1+sgh[128+tid]);
            float n=tanhf(gx2+r*sgh[256+tid]);
            float hn=(1.f-z)*n+z*hreg;
            hreg=hn;
            hidden[((size_t)t*128+b)*128+tid]=hn;
            shb[tid]=f2bf(hn);
        }
        __syncthreads();
        gx0=nx0; gx1=nx1; gx2=nx2;
    }
}

// ---------------------------------------------------------------------------
// Phase 4 fused: logits -> row softmax -> * mask -> out. 16 rows/block,
// 320 threads (5 waves), one class column per thread (283 active).
__global__ __launch_bounds__(320,2) void logits_softmax_kernel(
    const float* __restrict__ hidden, const float* __restrict__ W_out,
    const float* __restrict__ b_out, const float* __restrict__ mask,
    float* __restrict__ out)
{
    __shared__ float shd[2048];
    __shared__ float slog[16*288];
    const int tid=threadIdx.x;
    const int rb=blockIdx.x*16;
    for (int i=tid;i<2048;i+=320) shd[i]=hidden[(size_t)rb*128+i];
    __syncthreads();

    const bool act=(tid<283);
    const int cl=act? tid : 282;
    float acc[16];
    #pragma unroll
    for (int r=0;r<16;++r) acc[r]=0.f;
    for (int h=0;h<128;++h){
        float w0=W_out[h*283+cl];
        #pragma unroll
        for (int r=0;r<16;++r) acc[r]=fmaf(shd[r*128+h],w0,acc[r]);
    }
    float b0=b_out[cl];
    if (act){
        #pragma unroll
        for (int r=0;r<16;++r) slog[r*288+tid]=acc[r]+b0;
    }
    __syncthreads();

    // softmax: waves 0..3 handle 4 rows each
    const int wv=tid>>6, lane=tid&63;
    if (wv<4){
        #pragma unroll
        for (int rr=0;rr<4;++rr){
            int r=wv*4+rr;
            int m=rb+r;
            float v[5];
            float mx=-1e30f;
            #pragma unroll
            for (int i=0;i<5;++i){
                int c=lane+i*64;
                v[i]=(c<283)? slog[r*288+c] : -1e30f;
                mx=fmaxf(mx,v[i]);
            }
            #pragma unroll
            for (int off=32;off>0;off>>=1) mx=fmaxf(mx,__shfl_xor(mx,off,64));
            float s=0.f;
            #pragma unroll
            for (int i=0;i<5;++i){
                int c=lane+i*64;
                v[i]=(c<283)? __expf(v[i]-mx) : 0.f;
                s+=v[i];
            }
            #pragma unroll
            for (int off=32;off>0;off>>=1) s+=__shfl_xor(s,off,64);
            const float sc=mask[m]/s;
            float* op=out+(size_t)m*283;
            #pragma unroll
            for (int i=0;i<5;++i){
                int c=lane+i*64;
                if (c<283) op[c]=v[i]*sc;
            }
        }
    }
}

// ---------------------------------------------------------------------------
extern "C" void kernel_launch(void* const* d_in, const int* in_sizes, int n_in,
                              void* d_out, int out_size, void* d_ws, size_t ws_size,
                              hipStream_t stream) {
    const float* x      = (const float*)d_in[0];    // [50,128,8000]
    const float* mask   = (const float*)d_in[1];    // [50,128]
    const float* W_emb  = (const float*)d_in[2];    // [8728,128]
    const float* W_att  = (const float*)d_in[3];    // [256,100]
    const float* b_att  = (const float*)d_in[4];    // [100]
    const float* v_att  = (const float*)d_in[5];    // [100]
    const float* w_ih   = (const float*)d_in[6];    // [384,128]
    const float* w_hh   = (const float*)d_in[7];    // [384,128]
    const float* b_ih   = (const float*)d_in[8];    // [384]
    const float* b_hh   = (const float*)d_in[9];    // [384]
    const float* W_out  = (const float*)d_in[10];   // [128,283]
    const float* b_out  = (const float*)d_in[11];   // [283]
    const int* leaves   = (const int*)d_in[12];     // [8000,5]
    const int* anc      = (const int*)d_in[13];     // [8000,5]
    float* out = (float*)d_out;                     // [50,128,283] fp32

    char* w = (char*)d_ws;                          // no overlays
    u16*   WT_h    = (u16*)(w + 0);                 //    57,344
    u16*   WT_l    = (u16*)(w + 57344);             //    57,344
    u32*   whh_p   = (u32*)(w + 114688);            //    98,304
    float* w_ihT   = (float*)(w + 212992);          //   196,608
    u16*   emb_hiT = (u16*)(w + 409600);            // 2,048,000
    u16*   emb_loT = (u16*)(w + 2457600);           // 2,048,000
    float* emb_f   = (float*)(w + 4505600);         // 4,096,000
    float* partials= (float*)(w + 8601600);         // 16,384,000  [5][6400][128]
    float* GX      = (float*)(w + 24985600);        // 9,830,400   [6400][384]
    float* hidden  = (float*)(w + 34816000);        // 3,276,800   [6400][128]

    prep_kernel<<<400, 256, 0, stream>>>(W_att, WT_h, WT_l, w_hh, whh_p, w_ih, w_ihT);
    attn_mlp_kernel<<<320, 256, 0, stream>>>(W_emb, b_att, v_att, leaves, anc,
                                             WT_h, WT_l, emb_f);
    emb_split_kernel<<<125, 256, 0, stream>>>(emb_f, emb_hiT, emb_loT);
    gemm_xemb_kernel<<<500, 256, 0, stream>>>(x, emb_hiT, emb_loT, partials);
    sumtanh_gx_kernel<<<400, 384, 0, stream>>>(partials, w_ihT, b_ih, GX);
    gru_scan_kernel<<<128, 384, 0, stream>>>(whh_p, b_hh, GX, hidden);
    logits_softmax_kernel<<<400, 320, 0, stream>>>(hidden, W_out, b_out, mask, out);
}